// Round 2
// baseline (2155.760 us; speedup 1.0000x reference)
//
#include <hip/hip_runtime.h>
#include <hip/hip_bf16.h>
#include <math.h>

typedef __hip_bfloat16 bf16;
typedef __attribute__((ext_vector_type(8))) short short8;
typedef __attribute__((ext_vector_type(4))) float floatx4;

#define N_TOK 2048
#define DM    1024
#define NH    16
#define NKV   4
#define DH    64
#define NE    8
#define FF    2048
#define CH    64

__device__ __forceinline__ bf16 f2b(float x) { return __float2bfloat16(x); }
__device__ __forceinline__ short f2s(float x) { bf16 t = __float2bfloat16(x); return *(short*)&t; }

__device__ __forceinline__ float blockReduceSum256(float v) {
    __shared__ float tmp[4];
    #pragma unroll
    for (int m = 1; m < 64; m <<= 1) v += __shfl_xor(v, m, 64);
    if ((threadIdx.x & 63) == 0) tmp[threadIdx.x >> 6] = v;
    __syncthreads();
    float r = tmp[0] + tmp[1] + tmp[2] + tmp[3];
    __syncthreads();
    return r;
}

// ---------------- K1: rmsnorm (row) ----------------
__global__ __launch_bounds__(256) void k_rmsnorm(const float* __restrict__ in,
                                                 const float* __restrict__ w,
                                                 float* __restrict__ out) {
    int n = blockIdx.x;
    const float* row = in + (long)n * DM;
    float ss = 0.f;
    float vals[4];
    #pragma unroll
    for (int i = 0; i < 4; i++) {
        int c = threadIdx.x + i * 256;
        vals[i] = row[c];
        ss += vals[i] * vals[i];
    }
    float tot = blockReduceSum256(ss);
    float r = rsqrtf(tot / (float)DM + 1e-6f);
    float* orow = out + (long)n * DM;
    #pragma unroll
    for (int i = 0; i < 4; i++) {
        int c = threadIdx.x + i * 256;
        orow[c] = vals[i] * r * w[c];
    }
}

// ---------------- generic 128x128 MFMA GEMM (fp32 in/out, bf16 MFMA) -------
#define GEMM_ACC   1
#define GEMM_WRITE 2
#define GEMM_BIAS  4
#define GEMM_DOWN  8

__global__ __launch_bounds__(256) void k_gemm128(
    const float* __restrict__ A, int lda,
    const float* __restrict__ B, int ldb, long strideBe,
    float* __restrict__ C, int ldc,
    const float* __restrict__ bias,
    int K, int flags,
    const int* __restrict__ grp_off,
    const int* __restrict__ perm,
    const float* __restrict__ resid,
    float* __restrict__ outp)
{
    __shared__ __align__(16) short As[128 * 40];
    __shared__ __align__(16) short Bs[128 * 40];
    int tid = threadIdx.x;
    int e = blockIdx.z;
    int rowBase, rowsValid;
    const float* Bp = B;
    if (grp_off) {
        int r0 = grp_off[e], r1 = grp_off[e + 1];
        int rt = blockIdx.y * 128;
        rowsValid = (r1 - r0) - rt;
        if (rowsValid <= 0) return;
        if (rowsValid > 128) rowsValid = 128;
        rowBase = r0 + rt;
        Bp = B + (long)e * strideBe;
    } else {
        rowBase = blockIdx.y * 128;
        rowsValid = 128;
    }
    int n0 = blockIdx.x * 128;

    floatx4 acc[4][4];
    #pragma unroll
    for (int i = 0; i < 4; i++)
        #pragma unroll
        for (int j = 0; j < 4; j++) acc[i][j] = (floatx4){0.f, 0.f, 0.f, 0.f};

    int wave = tid >> 6, lane = tid & 63;
    int wm = (wave >> 1) * 64, wn = (wave & 1) * 64;
    int lrow = lane & 15, quad = lane >> 4;

    for (int k0 = 0; k0 < K; k0 += 32) {
        // stage A: 128 rows x 32 k (fp32 -> bf16), row-major k-contiguous
        #pragma unroll
        for (int i = 0; i < 4; i++) {
            int lin = tid + i * 256;            // 0..1023
            int r = lin >> 3, c4 = (lin & 7) << 2;
            floatx4 v = (floatx4){0.f, 0.f, 0.f, 0.f};
            if (r < rowsValid)
                v = *(const floatx4*)(A + (long)(rowBase + r) * lda + k0 + c4);
            short* dst = &As[r * 40 + c4];
            #pragma unroll
            for (int j = 0; j < 4; j++) dst[j] = f2s(v[j]);
        }
        // stage B transposed: Bs[n][k]  (B is K x N row-major fp32)
        #pragma unroll
        for (int i = 0; i < 4; i++) {
            int lin = tid + i * 256;            // 0..1023
            int kk = lin >> 5, nc = (lin & 31) << 2;
            floatx4 v = *(const floatx4*)(Bp + (long)(k0 + kk) * ldb + n0 + nc);
            #pragma unroll
            for (int j = 0; j < 4; j++) Bs[(nc + j) * 40 + kk] = f2s(v[j]);
        }
        __syncthreads();
        short8 af[4], bfr[4];
        #pragma unroll
        for (int mi = 0; mi < 4; mi++)
            af[mi] = *(const short8*)(&As[(wm + mi * 16 + lrow) * 40 + quad * 8]);
        #pragma unroll
        for (int ni = 0; ni < 4; ni++)
            bfr[ni] = *(const short8*)(&Bs[(wn + ni * 16 + lrow) * 40 + quad * 8]);
        #pragma unroll
        for (int mi = 0; mi < 4; mi++)
            #pragma unroll
            for (int ni = 0; ni < 4; ni++)
                acc[mi][ni] = __builtin_amdgcn_mfma_f32_16x16x32_bf16(
                    af[mi], bfr[ni], acc[mi][ni], 0, 0, 0);
        __syncthreads();
    }

    #pragma unroll
    for (int mi = 0; mi < 4; mi++) {
        #pragma unroll
        for (int ni = 0; ni < 4; ni++) {
            #pragma unroll
            for (int r = 0; r < 4; r++) {
                int rl = wm + mi * 16 + quad * 4 + r;
                if (rl >= rowsValid) continue;
                int grow = rowBase + rl;
                int gcol = n0 + wn + ni * 16 + lrow;
                float v = acc[mi][ni][r];
                if (flags & GEMM_BIAS) v += bias[gcol];
                if (flags & GEMM_DOWN) {
                    int tok = perm[grow];
                    long oi = (long)tok * ldc + gcol;
                    outp[oi] = resid[oi] + v;
                } else {
                    long ci = (long)grow * ldc + gcol;
                    if (flags & GEMM_ACC) v += C[ci];
                    if (flags & GEMM_WRITE) C[ci] = v;
                }
            }
        }
    }
}

// ---------------- K3: qk norm + rope + split ----------------
__global__ __launch_bounds__(256) void k_qkv_post(
    const float* __restrict__ qkv, const int* __restrict__ positions,
    const float* __restrict__ qnw, const float* __restrict__ knw,
    float* __restrict__ q, float* __restrict__ k, float* __restrict__ v)
{
    int n = blockIdx.x;
    int wave = threadIdx.x >> 6, lane = threadIdx.x & 63;
    float pos = (float)positions[n];
    int i = lane & 31;
    float invf = powf(10000.f, -((float)(2 * i)) / 64.f);
    float ang = pos * invf;
    float c = cosf(ang), s = sinf(ang);

    #pragma unroll
    for (int si = 0; si < 6; si++) {
        int slot = wave + si * 4;  // 0..23
        long base = (long)n * 1536 +
                    (slot < 16 ? slot * 64
                               : (slot < 20 ? 1024 + (slot - 16) * 64
                                            : 1280 + (slot - 20) * 64));
        float val = qkv[base + lane];
        if (slot < 20) {
            float ss = val * val;
            #pragma unroll
            for (int m = 1; m < 64; m <<= 1) ss += __shfl_xor(ss, m, 64);
            float r = rsqrtf(ss / 64.f + 1e-6f);
            float wn = (slot < 16 ? qnw[lane] : knw[lane]);
            float xn = val * r * wn;
            float partner = __shfl_xor(xn, 32, 64);
            float out = (lane < 32) ? (xn * c - partner * s) : (xn * c + partner * s);
            if (slot < 16) q[((long)n * NH + slot) * 64 + lane] = out;
            else           k[((long)n * NKV + (slot - 16)) * 64 + lane] = out;
        } else {
            v[((long)n * NKV + (slot - 20)) * 64 + lane] = val;
        }
    }
}

// ---------------- K4: flash attention ----------------
__global__ __launch_bounds__(256) void k_attn(
    const float* __restrict__ q, const float* __restrict__ k,
    const float* __restrict__ v, float* __restrict__ attn_out)
{
    const int h = blockIdx.y;
    const int qbase = blockIdx.x * 64;
    const int kvh = h >> 2;
    __shared__ __align__(16) short Qs[64 * 72];
    __shared__ __align__(16) short Ks[64 * 72];
    __shared__ __align__(16) short Vt[64 * 72];
    __shared__ __align__(16) short Ps[4 * 16 * 72];
    int tid = threadIdx.x, wave = tid >> 6, lane = tid & 63;
    int lrow = lane & 15, quad = lane >> 4;

    #pragma unroll
    for (int i = 0; i < 4; i++) {
        int lin = tid + i * 256;                // 0..1023
        int r = lin >> 4, dc = (lin & 15) << 2;
        floatx4 vq = *(const floatx4*)(q + ((long)(qbase + r) * NH + h) * 64 + dc);
        #pragma unroll
        for (int j = 0; j < 4; j++) Qs[r * 72 + dc + j] = f2s(vq[j]);
    }
    float m_i[4], l_i[4];
    floatx4 oacc[4];
    #pragma unroll
    for (int r = 0; r < 4; r++) { m_i[r] = -1e30f; l_i[r] = 0.f; }
    #pragma unroll
    for (int di = 0; di < 4; di++) oacc[di] = (floatx4){0.f, 0.f, 0.f, 0.f};
    const float scale = 0.125f;
    __syncthreads();

    for (int kt = 0; kt < N_TOK; kt += 64) {
        #pragma unroll
        for (int i = 0; i < 4; i++) {
            int lin = tid + i * 256;
            int r = lin >> 4, dc = (lin & 15) << 2;
            floatx4 k4 = *(const floatx4*)(k + ((long)(kt + r) * NKV + kvh) * 64 + dc);
            #pragma unroll
            for (int j = 0; j < 4; j++) Ks[r * 72 + dc + j] = f2s(k4[j]);
            floatx4 v4 = *(const floatx4*)(v + ((long)(kt + r) * NKV + kvh) * 64 + dc);
            #pragma unroll
            for (int j = 0; j < 4; j++) Vt[(dc + j) * 72 + r] = f2s(v4[j]);
        }
        __syncthreads();

        short8 aq0 = *(const short8*)&Qs[(wave * 16 + lrow) * 72 + quad * 8];
        short8 aq1 = *(const short8*)&Qs[(wave * 16 + lrow) * 72 + 32 + quad * 8];
        floatx4 sv[4];
        #pragma unroll
        for (int kn = 0; kn < 4; kn++) {
            short8 b0 = *(const short8*)&Ks[(kn * 16 + lrow) * 72 + quad * 8];
            short8 b1 = *(const short8*)&Ks[(kn * 16 + lrow) * 72 + 32 + quad * 8];
            floatx4 t = (floatx4){0.f, 0.f, 0.f, 0.f};
            t = __builtin_amdgcn_mfma_f32_16x16x32_bf16(aq0, b0, t, 0, 0, 0);
            t = __builtin_amdgcn_mfma_f32_16x16x32_bf16(aq1, b1, t, 0, 0, 0);
            sv[kn] = t;
        }
        #pragma unroll
        for (int kn = 0; kn < 4; kn++)
            #pragma unroll
            for (int r = 0; r < 4; r++) sv[kn][r] *= scale;

        #pragma unroll
        for (int r = 0; r < 4; r++) {
            float mx = fmaxf(fmaxf(sv[0][r], sv[1][r]), fmaxf(sv[2][r], sv[3][r]));
            #pragma unroll
            for (int msk = 1; msk < 16; msk <<= 1) mx = fmaxf(mx, __shfl_xor(mx, msk, 64));
            float mnew = fmaxf(m_i[r], mx);
            float alpha = __expf(m_i[r] - mnew);
            m_i[r] = mnew;
            l_i[r] *= alpha;
            #pragma unroll
            for (int di = 0; di < 4; di++) oacc[di][r] *= alpha;
            float rowsum = 0.f;
            #pragma unroll
            for (int kn = 0; kn < 4; kn++) {
                float p = __expf(sv[kn][r] - mnew);
                sv[kn][r] = p;
                rowsum += p;
            }
            #pragma unroll
            for (int msk = 1; msk < 16; msk <<= 1) rowsum += __shfl_xor(rowsum, msk, 64);
            l_i[r] += rowsum;
        }
        #pragma unroll
        for (int kn = 0; kn < 4; kn++)
            #pragma unroll
            for (int r = 0; r < 4; r++)
                Ps[(wave * 16 + quad * 4 + r) * 72 + kn * 16 + lrow] = f2s(sv[kn][r]);
        __syncthreads();

        short8 ap0 = *(const short8*)&Ps[(wave * 16 + lrow) * 72 + quad * 8];
        short8 ap1 = *(const short8*)&Ps[(wave * 16 + lrow) * 72 + 32 + quad * 8];
        #pragma unroll
        for (int di = 0; di < 4; di++) {
            short8 bv0 = *(const short8*)&Vt[(di * 16 + lrow) * 72 + quad * 8];
            short8 bv1 = *(const short8*)&Vt[(di * 16 + lrow) * 72 + 32 + quad * 8];
            oacc[di] = __builtin_amdgcn_mfma_f32_16x16x32_bf16(ap0, bv0, oacc[di], 0, 0, 0);
            oacc[di] = __builtin_amdgcn_mfma_f32_16x16x32_bf16(ap1, bv1, oacc[di], 0, 0, 0);
        }
        __syncthreads();
    }

    #pragma unroll
    for (int di = 0; di < 4; di++)
        #pragma unroll
        for (int r = 0; r < 4; r++) {
            float oval = oacc[di][r] / l_i[r];
            int n = qbase + wave * 16 + quad * 4 + r;
            attn_out[(long)n * DM + h * 64 + di * 16 + lrow] = oval;
        }
}

// ---------------- K5: fused ctrl / ODE / router / rmsnorm2 ----------------
__global__ __launch_bounds__(256) void k_ctrl(
    const float* __restrict__ o_f, const float* __restrict__ velocity,
    const float* __restrict__ mu_f, const float* __restrict__ hidden_in,
    const float* __restrict__ ctrl_in_w, const float* __restrict__ ctrl_in_b,
    const float* __restrict__ ctrl_out_w, const float* __restrict__ ctrl_out_b,
    const float* __restrict__ mu_router_w, const int* __restrict__ token_ids,
    const float* __restrict__ ln2_w,
    float* __restrict__ out_vnext, float* __restrict__ out_mu,
    float* __restrict__ hidden1_f, float* __restrict__ x_f,
    int* __restrict__ expert_id, int* __restrict__ counts)
{
    int n = blockIdx.x, tid = threadIdx.x;
    __shared__ float o_s[DM];
    __shared__ float vel_s[DM];
    __shared__ float mu_s[DM];
    __shared__ float ctrl_s[CH];
    __shared__ float co_s[3 * DM];
    __shared__ float red[8][64];

    #pragma unroll
    for (int i = 0; i < 4; i++) {
        int c = tid + i * 256;
        o_s[c] = o_f[(long)n * DM + c];
        vel_s[c] = velocity[(long)n * DM + c];
        mu_s[c] = mu_f[(long)n * DM + c];
    }
    __syncthreads();

    // ctrl = silu(hv @ W_in + b)
    {
        int c = tid & 63, kc = tid >> 6;
        float acc = 0.f;
        for (int k = kc * 512; k < kc * 512 + 512; k++) {
            float hv = (k < DM) ? o_s[k] : vel_s[k - DM];
            acc += hv * ctrl_in_w[k * CH + c];
        }
        red[kc][c] = acc;
    }
    __syncthreads();
    if (tid < 64) {
        float a = red[0][tid] + red[1][tid] + red[2][tid] + red[3][tid] + ctrl_in_b[tid];
        ctrl_s[tid] = a / (1.f + __expf(-a));
    }
    __syncthreads();

    // co = ctrl @ W_out + b
    for (int j = tid; j < 3 * DM; j += 256) {
        float a = ctrl_out_b[j];
        #pragma unroll
        for (int kk = 0; kk < CH; kk++) a += ctrl_s[kk] * ctrl_out_w[kk * (3 * DM) + j];
        co_s[j] = a;
    }
    __syncthreads();

    // router: mu_logits = mu_cur @ Wr ; argmax(one_hot*10 + logits)
    if (tid < 64) {
        int e = tid & 7, kc = tid >> 3;
        float a = 0.f;
        for (int k = kc * 128; k < kc * 128 + 128; k++)
            a += mu_s[k] * mu_router_w[k * NE + e];
        red[kc][e] = a;
    }
    __syncthreads();
    if (tid == 0) {
        int bid = token_ids[n] & (NE - 1);
        float best = -1e30f; int bi = 0;
        for (int e = 0; e < NE; e++) {
            float lg = red[0][e] + red[1][e] + red[2][e] + red[3][e] +
                       red[4][e] + red[5][e] + red[6][e] + red[7][e] +
                       (e == bid ? 10.f : 0.f);
            if (lg > best) { best = lg; bi = e; }
        }
        expert_id[n] = bi;
        atomicAdd(&counts[bi], 1);
    }

    // elementwise ODE + residual + write outputs
    float ssq = 0.f;
    float h1v[4];
    #pragma unroll
    for (int i = 0; i < 4; i++) {
        int c = tid + i * 256;
        float alpha = 1.f / (1.f + __expf(-co_s[c]));
        float braw = co_s[DM + c];
        float sp = (braw > 20.f) ? braw : log1pf(__expf(braw));
        float beta = fminf(sp, 2.0f);
        float gate = 1.f / (1.f + __expf(-co_s[2 * DM + c]));
        float err = o_s[c] - mu_s[c];
        float vn = fminf(fmaxf(alpha * vel_s[c] - beta * err, -10.f), 10.f);
        float hn = o_s[c] + 0.1f * gate * vn;
        float h1 = hidden_in[(long)n * DM + c] + hn;
        h1v[i] = h1;
        ssq += h1 * h1;
        out_vnext[(long)n * DM + c] = vn;
        out_mu[(long)n * DM + c] = mu_s[c];
        hidden1_f[(long)n * DM + c] = h1;
    }
    float tot = blockReduceSum256(ssq);
    float rstd = rsqrtf(tot / (float)DM + 1e-6f);
    #pragma unroll
    for (int i = 0; i < 4; i++) {
        int c = tid + i * 256;
        x_f[(long)n * DM + c] = h1v[i] * rstd * ln2_w[c];
    }
}

// ---------------- MoE aux ----------------
__global__ void k_zero8(int* counts, int* fill) {
    if (threadIdx.x < NE) { counts[threadIdx.x] = 0; fill[threadIdx.x] = 0; }
}
__global__ void k_offsets(const int* counts, int* off) {
    if (threadIdx.x == 0) {
        int a = 0;
        for (int e = 0; e < NE; e++) { off[e] = a; a += counts[e]; }
        off[NE] = a;
    }
}
__global__ void k_scatter(const int* expert_id, const int* off, int* fill, int* perm) {
    int n = blockIdx.x * 256 + threadIdx.x;
    if (n < N_TOK) {
        int e = expert_id[n];
        int p = off[e] + atomicAdd(&fill[e], 1);
        perm[p] = n;
    }
}
__global__ __launch_bounds__(256) void k_gather(const int* __restrict__ perm,
                                                const float* __restrict__ x,
                                                float* __restrict__ xg) {
    int r = blockIdx.x;
    int tok = perm[r];
    const floatx4* src = (const floatx4*)(x + (long)tok * DM);
    floatx4* dst = (floatx4*)(xg + (long)r * DM);
    dst[threadIdx.x] = src[threadIdx.x];
}
__global__ __launch_bounds__(256) void k_silumul(const float* __restrict__ g,
                                                 const float* __restrict__ u,
                                                 float* __restrict__ mid) {
    long i = (long)blockIdx.x * 256 + threadIdx.x;
    float gv = g[i];
    float uv = u[i];
    mid[i] = gv / (1.f + __expf(-gv)) * uv;
}

// ---------------- launcher ----------------
extern "C" void kernel_launch(void* const* d_in, const int* in_sizes, int n_in,
                              void* d_out, int out_size, void* d_ws, size_t ws_size,
                              hipStream_t stream) {
    (void)in_sizes; (void)n_in; (void)out_size; (void)ws_size;
    const float* hidden     = (const float*)d_in[0];
    const int*   positions  = (const int*)d_in[1];
    const float* velocity   = (const float*)d_in[2];
    const int*   token_ids  = (const int*)d_in[3];
    const float* mu_prev    = (const float*)d_in[4];
    const float* ln1_w      = (const float*)d_in[5];
    const float* ln2_w      = (const float*)d_in[6];
    const float* wq         = (const float*)d_in[7];
    const float* wk         = (const float*)d_in[8];
    const float* wv         = (const float*)d_in[9];
    const float* wo         = (const float*)d_in[10];
    const float* w_mu_q     = (const float*)d_in[11];
    const float* w_mu_k     = (const float*)d_in[12];
    const float* w_mu_v     = (const float*)d_in[13];
    const float* qnorm_w    = (const float*)d_in[14];
    const float* knorm_w    = (const float*)d_in[15];
    const float* dyn_mu     = (const float*)d_in[16];
    const float* dyn_proj   = (const float*)d_in[17];
    const float* ctrl_in_w  = (const float*)d_in[18];
    const float* ctrl_in_b  = (const float*)d_in[19];
    const float* ctrl_out_w = (const float*)d_in[20];
    const float* ctrl_out_b = (const float*)d_in[21];
    const float* mu_router  = (const float*)d_in[22];
    const float* w_gate     = (const float*)d_in[23];
    const float* w_up       = (const float*)d_in[24];
    const float* w_down     = (const float*)d_in[25];

    float* out0 = (float*)d_out;                   // hidden
    float* out1 = out0 + (long)N_TOK * DM;         // v_next
    float* out2 = out1 + (long)N_TOK * DM;         // mu_cur

    char* p = (char*)d_ws;
    auto alloc = [&](size_t bytes) -> void* {
        void* r = (void*)p;
        p += (bytes + 255) & ~(size_t)255;
        return r;
    };
    float* h_f       = (float*)alloc((long)N_TOK * DM * 4);      // aliased: attn_f after qkv gemms
    float* qkv_f     = (float*)alloc((long)N_TOK * 1536 * 4);    // aliased: x_f after qkv_post
    float* q_f       = (float*)alloc((long)N_TOK * NH * DH * 4); // aliased: xg_f after attn
    float* k_f       = (float*)alloc((long)N_TOK * NKV * DH * 4);
    float* v_f       = (float*)alloc((long)N_TOK * NKV * DH * 4);
    float* o_f       = (float*)alloc((long)N_TOK * DM * 4);
    float* mu_f      = (float*)alloc((long)N_TOK * DM * 4);
    float* hidden1_f = (float*)alloc((long)N_TOK * DM * 4);
    float* g_f       = (float*)alloc((long)N_TOK * FF * 4);
    float* u_f       = (float*)alloc((long)N_TOK * FF * 4);
    int*   expert_id = (int*)  alloc(N_TOK * 4);
    int*   perm      = (int*)  alloc(N_TOK * 4);
    int*   counts    = (int*)  alloc(64 * 4);
    int*   fill      = (int*)  alloc(64 * 4);
    int*   offs      = (int*)  alloc(64 * 4);

    float* attn_f = h_f;    // h consumed by qkv gemms before attn written
    float* x_f    = qkv_f;  // qkv consumed by qkv_post before x written
    float* xg_f   = q_f;    // q consumed by attn before gather

    dim3 blk(256);
    k_zero8<<<1, 64, 0, stream>>>(counts, fill);
    k_rmsnorm<<<N_TOK, blk, 0, stream>>>(hidden, ln1_w, h_f);

    // qkv = h@[wq wk wv] + mu_prev@[w_mu_q w_mu_k w_mu_v]  (ldc=1536)
    k_gemm128<<<dim3(8, 16, 1), blk, 0, stream>>>(h_f, DM, wq, 1024, 0, qkv_f, 1536,
        nullptr, DM, GEMM_WRITE, nullptr, nullptr, nullptr, nullptr);
    k_gemm128<<<dim3(2, 16, 1), blk, 0, stream>>>(h_f, DM, wk, 256, 0, qkv_f + 1024, 1536,
        nullptr, DM, GEMM_WRITE, nullptr, nullptr, nullptr, nullptr);
    k_gemm128<<<dim3(2, 16, 1), blk, 0, stream>>>(h_f, DM, wv, 256, 0, qkv_f + 1280, 1536,
        nullptr, DM, GEMM_WRITE, nullptr, nullptr, nullptr, nullptr);
    k_gemm128<<<dim3(8, 16, 1), blk, 0, stream>>>(mu_prev, DM, w_mu_q, 1024, 0, qkv_f, 1536,
        nullptr, DM, GEMM_ACC | GEMM_WRITE, nullptr, nullptr, nullptr, nullptr);
    k_gemm128<<<dim3(2, 16, 1), blk, 0, stream>>>(mu_prev, DM, w_mu_k, 256, 0, qkv_f + 1024, 1536,
        nullptr, DM, GEMM_ACC | GEMM_WRITE, nullptr, nullptr, nullptr, nullptr);
    k_gemm128<<<dim3(2, 16, 1), blk, 0, stream>>>(mu_prev, DM, w_mu_v, 256, 0, qkv_f + 1280, 1536,
        nullptr, DM, GEMM_ACC | GEMM_WRITE, nullptr, nullptr, nullptr, nullptr);

    k_qkv_post<<<N_TOK, blk, 0, stream>>>(qkv_f, positions, qnorm_w, knorm_w, q_f, k_f, v_f);
    k_attn<<<dim3(32, 16, 1), blk, 0, stream>>>(q_f, k_f, v_f, attn_f);

    // o = attn_out @ wo
    k_gemm128<<<dim3(8, 16, 1), blk, 0, stream>>>(attn_f, DM, wo, 1024, 0, o_f, DM,
        nullptr, DM, GEMM_WRITE, nullptr, nullptr, nullptr, nullptr);
    // mu_cur = dyn_mu + o @ dyn_proj
    k_gemm128<<<dim3(8, 16, 1), blk, 0, stream>>>(o_f, DM, dyn_proj, 1024, 0, mu_f, DM,
        dyn_mu, DM, GEMM_WRITE | GEMM_BIAS, nullptr, nullptr, nullptr, nullptr);

    k_ctrl<<<N_TOK, blk, 0, stream>>>(o_f, velocity, mu_f, hidden, ctrl_in_w, ctrl_in_b,
        ctrl_out_w, ctrl_out_b, mu_router, token_ids, ln2_w,
        out1, out2, hidden1_f, x_f, expert_id, counts);

    k_offsets<<<1, 64, 0, stream>>>(counts, offs);
    k_scatter<<<NE, blk, 0, stream>>>(expert_id, offs, fill, perm);
    k_gather<<<N_TOK, blk, 0, stream>>>(perm, x_f, xg_f);

    // grouped MoE: gate / up
    k_gemm128<<<dim3(16, 16, NE), blk, 0, stream>>>(xg_f, DM, w_gate, FF, (long)DM * FF,
        g_f, FF, nullptr, DM, GEMM_WRITE, offs, nullptr, nullptr, nullptr);
    k_gemm128<<<dim3(16, 16, NE), blk, 0, stream>>>(xg_f, DM, w_up, FF, (long)DM * FF,
        u_f, FF, nullptr, DM, GEMM_WRITE, offs, nullptr, nullptr, nullptr);
    k_silumul<<<(N_TOK * FF) / 256, blk, 0, stream>>>(g_f, u_f, g_f);
    // down + scatter + residual -> out0
    k_gemm128<<<dim3(8, 16, NE), blk, 0, stream>>>(g_f, FF, w_down, DM, (long)FF * DM,
        nullptr, DM, nullptr, FF, GEMM_DOWN, offs, perm, hidden1_f, out0);
}

// Round 3
// 1786.645 us; speedup vs baseline: 1.2066x; 1.2066x over previous
//
#include <hip/hip_runtime.h>
#include <hip/hip_bf16.h>
#include <math.h>

typedef __hip_bfloat16 bf16;
typedef __attribute__((ext_vector_type(8))) short short8;
typedef __attribute__((ext_vector_type(4))) float floatx4;

#define N_TOK 2048
#define DM    1024
#define NH    16
#define NKV   4
#define DH    64
#define NE    8
#define FF    2048
#define CH    64

__device__ __forceinline__ bf16 f2b(float x) { return __float2bfloat16(x); }
__device__ __forceinline__ short f2s(float x) { bf16 t = __float2bfloat16(x); return *(short*)&t; }

__device__ __forceinline__ float blockReduceSum256(float v) {
    __shared__ float tmp[4];
    #pragma unroll
    for (int m = 1; m < 64; m <<= 1) v += __shfl_xor(v, m, 64);
    if ((threadIdx.x & 63) == 0) tmp[threadIdx.x >> 6] = v;
    __syncthreads();
    float r = tmp[0] + tmp[1] + tmp[2] + tmp[3];
    __syncthreads();
    return r;
}

// ---------------- K1: rmsnorm (row) ----------------
__global__ __launch_bounds__(256) void k_rmsnorm(const float* __restrict__ in,
                                                 const float* __restrict__ w,
                                                 float* __restrict__ out) {
    int n = blockIdx.x;
    const float* row = in + (long)n * DM;
    float ss = 0.f;
    float vals[4];
    #pragma unroll
    for (int i = 0; i < 4; i++) {
        int c = threadIdx.x + i * 256;
        vals[i] = row[c];
        ss += vals[i] * vals[i];
    }
    float tot = blockReduceSum256(ss);
    float r = rsqrtf(tot / (float)DM + 1e-6f);
    float* orow = out + (long)n * DM;
    #pragma unroll
    for (int i = 0; i < 4; i++) {
        int c = threadIdx.x + i * 256;
        orow[c] = vals[i] * r * w[c];
    }
}

// ---------------- generic 128x128 MFMA GEMM (fp32 in/out, bf16 MFMA) -------
#define GEMM_ACC   1
#define GEMM_WRITE 2
#define GEMM_BIAS  4
#define GEMM_DOWN  8
#define GEMM_SILU  16

__global__ __launch_bounds__(256) void k_gemm128(
    const float* __restrict__ A, int lda,
    const float* __restrict__ B, int ldb, long strideBe,
    float* __restrict__ C, int ldc,
    const float* __restrict__ bias,
    int K, int flags,
    const int* __restrict__ grp_off,
    const int* __restrict__ perm,
    const float* __restrict__ resid,
    float* __restrict__ outp)
{
    __shared__ __align__(16) short As[128 * 40];
    __shared__ __align__(16) short Bs[128 * 40];
    int tid = threadIdx.x;
    int e = blockIdx.z;
    int rowBase, rowsValid;
    const float* Bp = B;
    if (grp_off) {
        int r0 = grp_off[e], r1 = grp_off[e + 1];
        int rt = blockIdx.y * 128;
        rowsValid = (r1 - r0) - rt;
        if (rowsValid <= 0) return;
        if (rowsValid > 128) rowsValid = 128;
        rowBase = r0 + rt;
        Bp = B + (long)e * strideBe;
    } else {
        rowBase = blockIdx.y * 128;
        rowsValid = 128;
    }
    int n0 = blockIdx.x * 128;

    floatx4 acc[4][4];
    #pragma unroll
    for (int i = 0; i < 4; i++)
        #pragma unroll
        for (int j = 0; j < 4; j++) acc[i][j] = (floatx4){0.f, 0.f, 0.f, 0.f};

    int wave = tid >> 6, lane = tid & 63;
    int wm = (wave >> 1) * 64, wn = (wave & 1) * 64;
    int lrow = lane & 15, quad = lane >> 4;

    for (int k0 = 0; k0 < K; k0 += 32) {
        // stage A: 128 rows x 32 k (fp32 -> bf16), row-major k-contiguous
        #pragma unroll
        for (int i = 0; i < 4; i++) {
            int lin = tid + i * 256;            // 0..1023
            int r = lin >> 3, c4 = (lin & 7) << 2;
            floatx4 v = (floatx4){0.f, 0.f, 0.f, 0.f};
            if (r < rowsValid)
                v = *(const floatx4*)(A + (long)(rowBase + r) * lda + k0 + c4);
            if (flags & GEMM_SILU) {
                #pragma unroll
                for (int j = 0; j < 4; j++) v[j] = v[j] / (1.f + __expf(-v[j]));
            }
            short* dst = &As[r * 40 + c4];
            #pragma unroll
            for (int j = 0; j < 4; j++) dst[j] = f2s(v[j]);
        }
        // stage B transposed: Bs[n][k]  (B is K x N row-major fp32)
        #pragma unroll
        for (int i = 0; i < 4; i++) {
            int lin = tid + i * 256;            // 0..1023
            int kk = lin >> 5, nc = (lin & 31) << 2;
            floatx4 v = *(const floatx4*)(Bp + (long)(k0 + kk) * ldb + n0 + nc);
            #pragma unroll
            for (int j = 0; j < 4; j++) Bs[(nc + j) * 40 + kk] = f2s(v[j]);
        }
        __syncthreads();
        short8 af[4], bfr[4];
        #pragma unroll
        for (int mi = 0; mi < 4; mi++)
            af[mi] = *(const short8*)(&As[(wm + mi * 16 + lrow) * 40 + quad * 8]);
        #pragma unroll
        for (int ni = 0; ni < 4; ni++)
            bfr[ni] = *(const short8*)(&Bs[(wn + ni * 16 + lrow) * 40 + quad * 8]);
        #pragma unroll
        for (int mi = 0; mi < 4; mi++)
            #pragma unroll
            for (int ni = 0; ni < 4; ni++)
                acc[mi][ni] = __builtin_amdgcn_mfma_f32_16x16x32_bf16(
                    af[mi], bfr[ni], acc[mi][ni], 0, 0, 0);
        __syncthreads();
    }

    #pragma unroll
    for (int mi = 0; mi < 4; mi++) {
        #pragma unroll
        for (int ni = 0; ni < 4; ni++) {
            #pragma unroll
            for (int r = 0; r < 4; r++) {
                int rl = wm + mi * 16 + quad * 4 + r;
                if (rl >= rowsValid) continue;
                int grow = rowBase + rl;
                int gcol = n0 + wn + ni * 16 + lrow;
                float v = acc[mi][ni][r];
                if (flags & GEMM_BIAS) v += bias[gcol];
                if (flags & GEMM_DOWN) {
                    int tok = perm[grow];
                    long oi = (long)tok * ldc + gcol;
                    outp[oi] = resid[oi] + v;
                } else {
                    long ci = (long)grow * ldc + gcol;
                    if (flags & GEMM_ACC) v += C[ci];
                    if (flags & GEMM_WRITE) C[ci] = v;
                }
            }
        }
    }
}

// ---------------- ctrl GEMM part 1: ctrl_raw += [o|vel] @ W_in (split-K) ---
__global__ __launch_bounds__(256) void k_ctrl_gemm(
    const float* __restrict__ o_f, const float* __restrict__ vel,
    const float* __restrict__ w_in, float* __restrict__ ctrl_raw)
{
    __shared__ __align__(16) short As[128 * 40];
    __shared__ __align__(16) short Bs[64 * 40];
    int tid = threadIdx.x;
    int rowBase = blockIdx.x * 128;
    int kchunk = blockIdx.y;                 // 0..15
    const float* A = (kchunk < 8) ? o_f : vel;
    int akoff = (kchunk & 7) * 128;
    int bkoff = kchunk * 128;

    floatx4 acc[2][4];
    #pragma unroll
    for (int i = 0; i < 2; i++)
        #pragma unroll
        for (int j = 0; j < 4; j++) acc[i][j] = (floatx4){0.f, 0.f, 0.f, 0.f};

    int wave = tid >> 6, lane = tid & 63;
    int wm = wave * 32;
    int lrow = lane & 15, quad = lane >> 4;

    for (int k0 = 0; k0 < 128; k0 += 32) {
        #pragma unroll
        for (int i = 0; i < 4; i++) {
            int lin = tid + i * 256;
            int r = lin >> 3, c4 = (lin & 7) << 2;
            floatx4 v = *(const floatx4*)(A + (long)(rowBase + r) * DM + akoff + k0 + c4);
            short* dst = &As[r * 40 + c4];
            #pragma unroll
            for (int j = 0; j < 4; j++) dst[j] = f2s(v[j]);
        }
        #pragma unroll
        for (int i = 0; i < 2; i++) {
            int lin = tid + i * 256;             // 0..511
            int kk = lin >> 4, nc = (lin & 15) << 2;
            floatx4 v = *(const floatx4*)(w_in + (long)(bkoff + k0 + kk) * CH + nc);
            #pragma unroll
            for (int j = 0; j < 4; j++) Bs[(nc + j) * 40 + kk] = f2s(v[j]);
        }
        __syncthreads();
        short8 af[2], bfr[4];
        #pragma unroll
        for (int mi = 0; mi < 2; mi++)
            af[mi] = *(const short8*)(&As[(wm + mi * 16 + lrow) * 40 + quad * 8]);
        #pragma unroll
        for (int ni = 0; ni < 4; ni++)
            bfr[ni] = *(const short8*)(&Bs[(ni * 16 + lrow) * 40 + quad * 8]);
        #pragma unroll
        for (int mi = 0; mi < 2; mi++)
            #pragma unroll
            for (int ni = 0; ni < 4; ni++)
                acc[mi][ni] = __builtin_amdgcn_mfma_f32_16x16x32_bf16(
                    af[mi], bfr[ni], acc[mi][ni], 0, 0, 0);
        __syncthreads();
    }

    #pragma unroll
    for (int mi = 0; mi < 2; mi++)
        #pragma unroll
        for (int ni = 0; ni < 4; ni++)
            #pragma unroll
            for (int r = 0; r < 4; r++) {
                int grow = rowBase + wm + mi * 16 + quad * 4 + r;
                int gcol = ni * 16 + lrow;
                atomicAdd(&ctrl_raw[(long)grow * CH + gcol], acc[mi][ni][r]);
            }
}

__global__ __launch_bounds__(256) void k_initb(const float* __restrict__ b,
                                               float* __restrict__ ctrl_raw) {
    int i = blockIdx.x * 256 + threadIdx.x;
    ctrl_raw[i] = b[i & (CH - 1)];
}

// ---------------- K3: qk norm + rope + split ----------------
__global__ __launch_bounds__(256) void k_qkv_post(
    const float* __restrict__ qkv, const int* __restrict__ positions,
    const float* __restrict__ qnw, const float* __restrict__ knw,
    float* __restrict__ q, float* __restrict__ k, float* __restrict__ v)
{
    int n = blockIdx.x;
    int wave = threadIdx.x >> 6, lane = threadIdx.x & 63;
    float pos = (float)positions[n];
    int i = lane & 31;
    float invf = powf(10000.f, -((float)(2 * i)) / 64.f);
    float ang = pos * invf;
    float c = cosf(ang), s = sinf(ang);

    #pragma unroll
    for (int si = 0; si < 6; si++) {
        int slot = wave + si * 4;  // 0..23
        long base = (long)n * 1536 +
                    (slot < 16 ? slot * 64
                               : (slot < 20 ? 1024 + (slot - 16) * 64
                                            : 1280 + (slot - 20) * 64));
        float val = qkv[base + lane];
        if (slot < 20) {
            float ss = val * val;
            #pragma unroll
            for (int m = 1; m < 64; m <<= 1) ss += __shfl_xor(ss, m, 64);
            float r = rsqrtf(ss / 64.f + 1e-6f);
            float wn = (slot < 16 ? qnw[lane] : knw[lane]);
            float xn = val * r * wn;
            float partner = __shfl_xor(xn, 32, 64);
            float out = (lane < 32) ? (xn * c - partner * s) : (xn * c + partner * s);
            if (slot < 16) q[((long)n * NH + slot) * 64 + lane] = out;
            else           k[((long)n * NKV + (slot - 16)) * 64 + lane] = out;
        } else {
            v[((long)n * NKV + (slot - 20)) * 64 + lane] = val;
        }
    }
}

// ---------------- K4: flash attention ----------------
__global__ __launch_bounds__(256) void k_attn(
    const float* __restrict__ q, const float* __restrict__ k,
    const float* __restrict__ v, float* __restrict__ attn_out)
{
    const int h = blockIdx.y;
    const int qbase = blockIdx.x * 64;
    const int kvh = h >> 2;
    __shared__ __align__(16) short Qs[64 * 72];
    __shared__ __align__(16) short Ks[64 * 72];
    __shared__ __align__(16) short Vt[64 * 72];
    __shared__ __align__(16) short Ps[4 * 16 * 72];
    int tid = threadIdx.x, wave = tid >> 6, lane = tid & 63;
    int lrow = lane & 15, quad = lane >> 4;

    #pragma unroll
    for (int i = 0; i < 4; i++) {
        int lin = tid + i * 256;                // 0..1023
        int r = lin >> 4, dc = (lin & 15) << 2;
        floatx4 vq = *(const floatx4*)(q + ((long)(qbase + r) * NH + h) * 64 + dc);
        #pragma unroll
        for (int j = 0; j < 4; j++) Qs[r * 72 + dc + j] = f2s(vq[j]);
    }
    float m_i[4], l_i[4];
    floatx4 oacc[4];
    #pragma unroll
    for (int r = 0; r < 4; r++) { m_i[r] = -1e30f; l_i[r] = 0.f; }
    #pragma unroll
    for (int di = 0; di < 4; di++) oacc[di] = (floatx4){0.f, 0.f, 0.f, 0.f};
    const float scale = 0.125f;
    __syncthreads();

    for (int kt = 0; kt < N_TOK; kt += 64) {
        #pragma unroll
        for (int i = 0; i < 4; i++) {
            int lin = tid + i * 256;
            int r = lin >> 4, dc = (lin & 15) << 2;
            floatx4 k4 = *(const floatx4*)(k + ((long)(kt + r) * NKV + kvh) * 64 + dc);
            #pragma unroll
            for (int j = 0; j < 4; j++) Ks[r * 72 + dc + j] = f2s(k4[j]);
            floatx4 v4 = *(const floatx4*)(v + ((long)(kt + r) * NKV + kvh) * 64 + dc);
            #pragma unroll
            for (int j = 0; j < 4; j++) Vt[(dc + j) * 72 + r] = f2s(v4[j]);
        }
        __syncthreads();

        short8 aq0 = *(const short8*)&Qs[(wave * 16 + lrow) * 72 + quad * 8];
        short8 aq1 = *(const short8*)&Qs[(wave * 16 + lrow) * 72 + 32 + quad * 8];
        floatx4 sv[4];
        #pragma unroll
        for (int kn = 0; kn < 4; kn++) {
            short8 b0 = *(const short8*)&Ks[(kn * 16 + lrow) * 72 + quad * 8];
            short8 b1 = *(const short8*)&Ks[(kn * 16 + lrow) * 72 + 32 + quad * 8];
            floatx4 t = (floatx4){0.f, 0.f, 0.f, 0.f};
            t = __builtin_amdgcn_mfma_f32_16x16x32_bf16(aq0, b0, t, 0, 0, 0);
            t = __builtin_amdgcn_mfma_f32_16x16x32_bf16(aq1, b1, t, 0, 0, 0);
            sv[kn] = t;
        }
        #pragma unroll
        for (int kn = 0; kn < 4; kn++)
            #pragma unroll
            for (int r = 0; r < 4; r++) sv[kn][r] *= scale;

        #pragma unroll
        for (int r = 0; r < 4; r++) {
            float mx = fmaxf(fmaxf(sv[0][r], sv[1][r]), fmaxf(sv[2][r], sv[3][r]));
            #pragma unroll
            for (int msk = 1; msk < 16; msk <<= 1) mx = fmaxf(mx, __shfl_xor(mx, msk, 64));
            float mnew = fmaxf(m_i[r], mx);
            float alpha = __expf(m_i[r] - mnew);
            m_i[r] = mnew;
            l_i[r] *= alpha;
            #pragma unroll
            for (int di = 0; di < 4; di++) oacc[di][r] *= alpha;
            float rowsum = 0.f;
            #pragma unroll
            for (int kn = 0; kn < 4; kn++) {
                float p = __expf(sv[kn][r] - mnew);
                sv[kn][r] = p;
                rowsum += p;
            }
            #pragma unroll
            for (int msk = 1; msk < 16; msk <<= 1) rowsum += __shfl_xor(rowsum, msk, 64);
            l_i[r] += rowsum;
        }
        #pragma unroll
        for (int kn = 0; kn < 4; kn++)
            #pragma unroll
            for (int r = 0; r < 4; r++)
                Ps[(wave * 16 + quad * 4 + r) * 72 + kn * 16 + lrow] = f2s(sv[kn][r]);
        __syncthreads();

        short8 ap0 = *(const short8*)&Ps[(wave * 16 + lrow) * 72 + quad * 8];
        short8 ap1 = *(const short8*)&Ps[(wave * 16 + lrow) * 72 + 32 + quad * 8];
        #pragma unroll
        for (int di = 0; di < 4; di++) {
            short8 bv0 = *(const short8*)&Vt[(di * 16 + lrow) * 72 + quad * 8];
            short8 bv1 = *(const short8*)&Vt[(di * 16 + lrow) * 72 + 32 + quad * 8];
            oacc[di] = __builtin_amdgcn_mfma_f32_16x16x32_bf16(ap0, bv0, oacc[di], 0, 0, 0);
            oacc[di] = __builtin_amdgcn_mfma_f32_16x16x32_bf16(ap1, bv1, oacc[di], 0, 0, 0);
        }
        __syncthreads();
    }

    #pragma unroll
    for (int di = 0; di < 4; di++)
        #pragma unroll
        for (int r = 0; r < 4; r++) {
            float oval = oacc[di][r] / l_i[r];
            int n = qbase + wave * 16 + quad * 4 + r;
            attn_out[(long)n * DM + h * 64 + di * 16 + lrow] = oval;
        }
}

// ---------------- K5: elementwise ODE + router + rmsnorm2 ----------------
__global__ __launch_bounds__(256) void k_ode(
    const float* __restrict__ co, const float* __restrict__ o_f,
    const float* __restrict__ velocity, const float* __restrict__ mu_f,
    const float* __restrict__ hidden_in,
    const float* __restrict__ mu_router_w, const int* __restrict__ token_ids,
    const float* __restrict__ ln2_w,
    float* __restrict__ out_vnext, float* __restrict__ out_mu,
    float* __restrict__ hidden1_f, float* __restrict__ x_f,
    int* __restrict__ expert_id, int* __restrict__ counts)
{
    int n = blockIdx.x, tid = threadIdx.x;
    __shared__ float mu_s[DM];
    __shared__ float red2[32][8];

    #pragma unroll
    for (int i = 0; i < 4; i++) {
        int c = tid + i * 256;
        mu_s[c] = mu_f[(long)n * DM + c];
    }
    __syncthreads();

    // router: mu_logits = mu_cur @ Wr ; argmax(one_hot*10 + logits)
    {
        int e = tid & 7, kc = tid >> 3;
        float a = 0.f;
        #pragma unroll
        for (int kk = 0; kk < 32; kk++) {
            int k = kc * 32 + kk;
            a += mu_s[k] * mu_router_w[k * NE + e];
        }
        red2[kc][e] = a;
    }
    __syncthreads();
    if (tid == 0) {
        int bid = token_ids[n] & (NE - 1);
        float best = -1e30f; int bi = 0;
        for (int e = 0; e < NE; e++) {
            float lg = (e == bid ? 10.f : 0.f);
            for (int j = 0; j < 32; j++) lg += red2[j][e];
            if (lg > best) { best = lg; bi = e; }
        }
        expert_id[n] = bi;
        atomicAdd(&counts[bi], 1);
    }

    // elementwise ODE + residual
    float ssq = 0.f;
    float h1v[4];
    #pragma unroll
    for (int i = 0; i < 4; i++) {
        int c = tid + i * 256;
        float coa = co[(long)n * 3072 + c];
        float cob = co[(long)n * 3072 + DM + c];
        float cog = co[(long)n * 3072 + 2 * DM + c];
        float alpha = 1.f / (1.f + __expf(-coa));
        float sp = (cob > 20.f) ? cob : log1pf(__expf(cob));
        float beta = fminf(sp, 2.0f);
        float gate = 1.f / (1.f + __expf(-cog));
        float ov = o_f[(long)n * DM + c];
        float vv = velocity[(long)n * DM + c];
        float err = ov - mu_s[c];
        float vn = fminf(fmaxf(alpha * vv - beta * err, -10.f), 10.f);
        float hn = ov + 0.1f * gate * vn;
        float h1 = hidden_in[(long)n * DM + c] + hn;
        h1v[i] = h1;
        ssq += h1 * h1;
        out_vnext[(long)n * DM + c] = vn;
        out_mu[(long)n * DM + c] = mu_s[c];
        hidden1_f[(long)n * DM + c] = h1;
    }
    float tot = blockReduceSum256(ssq);
    float rstd = rsqrtf(tot / (float)DM + 1e-6f);
    #pragma unroll
    for (int i = 0; i < 4; i++) {
        int c = tid + i * 256;
        x_f[(long)n * DM + c] = h1v[i] * rstd * ln2_w[c];
    }
}

// ---------------- MoE aux ----------------
__global__ void k_zero8(int* counts, int* fill) {
    if (threadIdx.x < NE) { counts[threadIdx.x] = 0; fill[threadIdx.x] = 0; }
}
__global__ void k_offsets(const int* counts, int* off) {
    if (threadIdx.x == 0) {
        int a = 0;
        for (int e = 0; e < NE; e++) { off[e] = a; a += counts[e]; }
        off[NE] = a;
    }
}
__global__ void k_scatter(const int* expert_id, const int* off, int* fill, int* perm) {
    int n = blockIdx.x * 256 + threadIdx.x;
    if (n < N_TOK) {
        int e = expert_id[n];
        int p = off[e] + atomicAdd(&fill[e], 1);
        perm[p] = n;
    }
}
__global__ __launch_bounds__(256) void k_gather(const int* __restrict__ perm,
                                                const float* __restrict__ x,
                                                float* __restrict__ xg) {
    int r = blockIdx.x;
    int tok = perm[r];
    const floatx4* src = (const floatx4*)(x + (long)tok * DM);
    floatx4* dst = (floatx4*)(xg + (long)r * DM);
    dst[threadIdx.x] = src[threadIdx.x];
}
__global__ __launch_bounds__(256) void k_silumul(const float* __restrict__ g,
                                                 const float* __restrict__ u,
                                                 float* __restrict__ mid) {
    long i = (long)blockIdx.x * 256 + threadIdx.x;
    float gv = g[i];
    float uv = u[i];
    mid[i] = gv / (1.f + __expf(-gv)) * uv;
}

// ---------------- launcher ----------------
extern "C" void kernel_launch(void* const* d_in, const int* in_sizes, int n_in,
                              void* d_out, int out_size, void* d_ws, size_t ws_size,
                              hipStream_t stream) {
    (void)in_sizes; (void)n_in; (void)out_size; (void)ws_size;
    const float* hidden     = (const float*)d_in[0];
    const int*   positions  = (const int*)d_in[1];
    const float* velocity   = (const float*)d_in[2];
    const int*   token_ids  = (const int*)d_in[3];
    const float* mu_prev    = (const float*)d_in[4];
    const float* ln1_w      = (const float*)d_in[5];
    const float* ln2_w      = (const float*)d_in[6];
    const float* wq         = (const float*)d_in[7];
    const float* wk         = (const float*)d_in[8];
    const float* wv         = (const float*)d_in[9];
    const float* wo         = (const float*)d_in[10];
    const float* w_mu_q     = (const float*)d_in[11];
    const float* w_mu_k     = (const float*)d_in[12];
    const float* w_mu_v     = (const float*)d_in[13];
    const float* qnorm_w    = (const float*)d_in[14];
    const float* knorm_w    = (const float*)d_in[15];
    const float* dyn_mu     = (const float*)d_in[16];
    const float* dyn_proj   = (const float*)d_in[17];
    const float* ctrl_in_w  = (const float*)d_in[18];
    const float* ctrl_in_b  = (const float*)d_in[19];
    const float* ctrl_out_w = (const float*)d_in[20];
    const float* ctrl_out_b = (const float*)d_in[21];
    const float* mu_router  = (const float*)d_in[22];
    const float* w_gate     = (const float*)d_in[23];
    const float* w_up       = (const float*)d_in[24];
    const float* w_down     = (const float*)d_in[25];

    float* out0 = (float*)d_out;                   // hidden
    float* out1 = out0 + (long)N_TOK * DM;         // v_next
    float* out2 = out1 + (long)N_TOK * DM;         // mu_cur

    char* p = (char*)d_ws;
    auto alloc = [&](size_t bytes) -> void* {
        void* r = (void*)p;
        p += (bytes + 255) & ~(size_t)255;
        return r;
    };
    float* h_f       = (float*)alloc((long)N_TOK * DM * 4);      // aliased: attn_f after qkv gemms
    float* qkv_f     = (float*)alloc((long)N_TOK * 1536 * 4);    // aliased: x_f after qkv_post
    float* q_f       = (float*)alloc((long)N_TOK * NH * DH * 4); // aliased: xg_f after attn
    float* k_f       = (float*)alloc((long)N_TOK * NKV * DH * 4);
    float* v_f       = (float*)alloc((long)N_TOK * NKV * DH * 4);
    float* o_f       = (float*)alloc((long)N_TOK * DM * 4);
    float* mu_f      = (float*)alloc((long)N_TOK * DM * 4);
    float* hidden1_f = (float*)alloc((long)N_TOK * DM * 4);
    float* moe_f     = (float*)alloc((long)N_TOK * FF * 2 * 4);  // co_f / g_f+u_f union
    float* ctrl_raw  = (float*)alloc((long)N_TOK * CH * 4);
    int*   expert_id = (int*)  alloc(N_TOK * 4);
    int*   perm      = (int*)  alloc(N_TOK * 4);
    int*   counts    = (int*)  alloc(64 * 4);
    int*   fill      = (int*)  alloc(64 * 4);
    int*   offs      = (int*)  alloc(64 * 4);

    float* attn_f = h_f;    // h consumed by qkv gemms before attn written
    float* x_f    = qkv_f;  // qkv consumed by qkv_post before x written
    float* xg_f   = q_f;    // q consumed by attn before gather
    float* co_f   = moe_f;  // co consumed by k_ode before g/u written
    float* g_f    = moe_f;
    float* u_f    = moe_f + (long)N_TOK * FF;

    dim3 blk(256);
    k_zero8<<<1, 64, 0, stream>>>(counts, fill);
    k_initb<<<(N_TOK * CH) / 256, blk, 0, stream>>>(ctrl_in_b, ctrl_raw);
    k_rmsnorm<<<N_TOK, blk, 0, stream>>>(hidden, ln1_w, h_f);

    // qkv = h@[wq wk wv] + mu_prev@[w_mu_q w_mu_k w_mu_v]  (ldc=1536)
    k_gemm128<<<dim3(8, 16, 1), blk, 0, stream>>>(h_f, DM, wq, 1024, 0, qkv_f, 1536,
        nullptr, DM, GEMM_WRITE, nullptr, nullptr, nullptr, nullptr);
    k_gemm128<<<dim3(2, 16, 1), blk, 0, stream>>>(h_f, DM, wk, 256, 0, qkv_f + 1024, 1536,
        nullptr, DM, GEMM_WRITE, nullptr, nullptr, nullptr, nullptr);
    k_gemm128<<<dim3(2, 16, 1), blk, 0, stream>>>(h_f, DM, wv, 256, 0, qkv_f + 1280, 1536,
        nullptr, DM, GEMM_WRITE, nullptr, nullptr, nullptr, nullptr);
    k_gemm128<<<dim3(8, 16, 1), blk, 0, stream>>>(mu_prev, DM, w_mu_q, 1024, 0, qkv_f, 1536,
        nullptr, DM, GEMM_ACC | GEMM_WRITE, nullptr, nullptr, nullptr, nullptr);
    k_gemm128<<<dim3(2, 16, 1), blk, 0, stream>>>(mu_prev, DM, w_mu_k, 256, 0, qkv_f + 1024, 1536,
        nullptr, DM, GEMM_ACC | GEMM_WRITE, nullptr, nullptr, nullptr, nullptr);
    k_gemm128<<<dim3(2, 16, 1), blk, 0, stream>>>(mu_prev, DM, w_mu_v, 256, 0, qkv_f + 1280, 1536,
        nullptr, DM, GEMM_ACC | GEMM_WRITE, nullptr, nullptr, nullptr, nullptr);

    k_qkv_post<<<N_TOK, blk, 0, stream>>>(qkv_f, positions, qnorm_w, knorm_w, q_f, k_f, v_f);
    k_attn<<<dim3(32, 16, 1), blk, 0, stream>>>(q_f, k_f, v_f, attn_f);

    // o = attn_out @ wo
    k_gemm128<<<dim3(8, 16, 1), blk, 0, stream>>>(attn_f, DM, wo, 1024, 0, o_f, DM,
        nullptr, DM, GEMM_WRITE, nullptr, nullptr, nullptr, nullptr);
    // mu_cur = dyn_mu + o @ dyn_proj
    k_gemm128<<<dim3(8, 16, 1), blk, 0, stream>>>(o_f, DM, dyn_proj, 1024, 0, mu_f, DM,
        dyn_mu, DM, GEMM_WRITE | GEMM_BIAS, nullptr, nullptr, nullptr, nullptr);

    // ctrl_raw = b_in + [o|vel] @ W_in   (split-K, atomic accumulate)
    k_ctrl_gemm<<<dim3(16, 16, 1), blk, 0, stream>>>(o_f, velocity, ctrl_in_w, ctrl_raw);
    // co = silu(ctrl_raw) @ W_out + b_out
    k_gemm128<<<dim3(24, 16, 1), blk, 0, stream>>>(ctrl_raw, CH, ctrl_out_w, 3072, 0, co_f, 3072,
        ctrl_out_b, CH, GEMM_WRITE | GEMM_BIAS | GEMM_SILU, nullptr, nullptr, nullptr, nullptr);

    k_ode<<<N_TOK, blk, 0, stream>>>(co_f, o_f, velocity, mu_f, hidden,
        mu_router, token_ids, ln2_w,
        out1, out2, hidden1_f, x_f, expert_id, counts);

    k_offsets<<<1, 64, 0, stream>>>(counts, offs);
    k_scatter<<<NE, blk, 0, stream>>>(expert_id, offs, fill, perm);
    k_gather<<<N_TOK, blk, 0, stream>>>(perm, x_f, xg_f);

    // grouped MoE: gate / up
    k_gemm128<<<dim3(16, 16, NE), blk, 0, stream>>>(xg_f, DM, w_gate, FF, (long)DM * FF,
        g_f, FF, nullptr, DM, GEMM_WRITE, offs, nullptr, nullptr, nullptr);
    k_gemm128<<<dim3(16, 16, NE), blk, 0, stream>>>(xg_f, DM, w_up, FF, (long)DM * FF,
        u_f, FF, nullptr, DM, GEMM_WRITE, offs, nullptr, nullptr, nullptr);
    k_silumul<<<(N_TOK * FF) / 256, blk, 0, stream>>>(g_f, u_f, g_f);
    // down + scatter + residual -> out0
    k_gemm128<<<dim3(8, 16, NE), blk, 0, stream>>>(g_f, FF, w_down, DM, (long)FF * DM,
        nullptr, DM, nullptr, FF, GEMM_DOWN, offs, perm, hidden1_f, out0);
}

// Round 5
// 765.510 us; speedup vs baseline: 2.8161x; 2.3339x over previous
//
#include <hip/hip_runtime.h>
#include <hip/hip_bf16.h>
#include <math.h>

typedef __hip_bfloat16 bf16;
typedef __attribute__((ext_vector_type(8))) short short8;
typedef __attribute__((ext_vector_type(4))) float floatx4;

#define N_TOK 2048
#define DM    1024
#define NH    16
#define NKV   4
#define DH    64
#define NE    8
#define FF    2048
#define CH    64

__device__ __forceinline__ float b2f(bf16 x) { return __bfloat162float(x); }
__device__ __forceinline__ bf16  f2b(float x) { return __float2bfloat16(x); }
__device__ __forceinline__ short f2s(float x) { bf16 t = __float2bfloat16(x); return *(short*)&t; }

// async global->LDS, 16B per lane; LDS dest = wave-uniform base + lane*16
#define GLL16(g, l) __builtin_amdgcn_global_load_lds( \
    (const __attribute__((address_space(1))) void*)(g), \
    (__attribute__((address_space(3))) void*)(l), 16, 0, 0)

__device__ __forceinline__ float blockReduceSum256(float v) {
    __shared__ float tmp[4];
    #pragma unroll
    for (int m = 1; m < 64; m <<= 1) v += __shfl_xor(v, m, 64);
    if ((threadIdx.x & 63) == 0) tmp[threadIdx.x >> 6] = v;
    __syncthreads();
    float r = tmp[0] + tmp[1] + tmp[2] + tmp[3];
    __syncthreads();
    return r;
}

// ---------------- transpose fp32 KxN -> bf16 NxK ----------------
__global__ __launch_bounds__(256) void k_transpose(
    const float* __restrict__ src, long sstrideE, int sN,
    bf16* __restrict__ dst, long dstrideE, int ldk)
{
    __shared__ float tile[64][65];
    const float* s = src + (long)blockIdx.z * sstrideE;
    bf16* d = dst + (long)blockIdx.z * dstrideE;
    int n0 = blockIdx.x * 64, k0 = blockIdx.y * 64;
    int tid = threadIdx.x;
    int c = tid & 63, r4 = tid >> 6;
    #pragma unroll
    for (int i = 0; i < 16; i++) {
        int r = i * 4 + r4;
        tile[r][c] = s[(long)(k0 + r) * sN + n0 + c];
    }
    __syncthreads();
    int c2 = (tid & 31) * 2, rr = tid >> 5;
    #pragma unroll
    for (int i = 0; i < 8; i++) {
        int r = i * 8 + rr;
        short2 o;
        o.x = f2s(tile[c2][r]);
        o.y = f2s(tile[c2 + 1][r]);
        *(short2*)(d + (long)(n0 + r) * ldk + k0 + c2) = o;
    }
}

// ---------------- fp32 row (len 1024) -> bf16 into stride-2048 buffer ------
__global__ __launch_bounds__(256) void k_cvt(const float* __restrict__ src,
                                             bf16* __restrict__ dst) {
    int n = blockIdx.x, tid = threadIdx.x;
    #pragma unroll
    for (int i = 0; i < 4; i++) {
        int c = tid + i * 256;
        dst[(long)n * 2048 + c] = f2b(src[(long)n * DM + c]);
    }
}

// ---------------- rmsnorm -> bf16 into catA[:, 0:1024] (stride 2048) ------
__global__ __launch_bounds__(256) void k_rmsnorm(const float* __restrict__ in,
                                                 const float* __restrict__ w,
                                                 bf16* __restrict__ out) {
    int n = blockIdx.x;
    const float* row = in + (long)n * DM;
    float ss = 0.f;
    float vals[4];
    #pragma unroll
    for (int i = 0; i < 4; i++) {
        int c = threadIdx.x + i * 256;
        vals[i] = row[c];
        ss += vals[i] * vals[i];
    }
    float tot = blockReduceSum256(ss);
    float r = rsqrtf(tot / (float)DM + 1e-6f);
    #pragma unroll
    for (int i = 0; i < 4; i++) {
        int c = threadIdx.x + i * 256;
        out[(long)n * 2048 + c] = f2b(vals[i] * r * w[c]);
    }
}

// ---------------- generic 128x128 MFMA GEMM, bf16 A (MxK) x bf16 B^T (NxK) -
#define GEMM_WRITE  1
#define GEMM_BIAS   2
#define GEMM_WRITEB 4
#define GEMM_DOWN   8

__global__ __launch_bounds__(256) void k_gemm(
    const bf16* __restrict__ A, int lda,
    const bf16* __restrict__ Bt, int ldb, long strideBe,
    float* __restrict__ C, int ldc,
    const float* __restrict__ bias,
    bf16* __restrict__ Cb, int ldcb,
    int K, int flags,
    const int* __restrict__ grp_off,
    const int* __restrict__ perm,
    float* __restrict__ outp)
{
    __shared__ __align__(16) short As[128 * 32];
    __shared__ __align__(16) short Bs[128 * 32];
    int tid = threadIdx.x;
    int e = blockIdx.z;
    int rowBase, rowsValid;
    const bf16* Bp = Bt;
    if (grp_off) {
        int r0 = grp_off[e], r1 = grp_off[e + 1];
        int rt = blockIdx.y * 128;
        rowsValid = (r1 - r0) - rt;
        if (rowsValid <= 0) return;
        if (rowsValid > 128) rowsValid = 128;
        rowBase = r0 + rt;
        Bp = Bt + (long)e * strideBe;
    } else {
        rowBase = blockIdx.y * 128;
        rowsValid = 128;
    }
    int n0 = blockIdx.x * 128;

    floatx4 acc[4][4];
    #pragma unroll
    for (int i = 0; i < 4; i++)
        #pragma unroll
        for (int j = 0; j < 4; j++) acc[i][j] = (floatx4){0.f, 0.f, 0.f, 0.f};

    int wave = tid >> 6, lane = tid & 63;
    int wm = (wave >> 1) * 64, wn = (wave & 1) * 64;
    int lrow = lane & 15, quad = lane >> 4;

    // staging map: chunk c covers LDS rows c*16..c*16+15 (row = 32 shorts = 64B)
    int c0 = wave * 2;
    int srow0 = c0 * 16 + (lane >> 2);
    int srow1 = (c0 + 1) * 16 + (lane >> 2);
    int skoff = (lane & 3) * 8;
    short* ldsA0 = As + c0 * 512;
    short* ldsA1 = As + (c0 + 1) * 512;
    short* ldsB0 = Bs + c0 * 512;
    short* ldsB1 = Bs + (c0 + 1) * 512;

    for (int k0 = 0; k0 < K; k0 += 32) {
        if (srow0 < rowsValid) GLL16(A + (long)(rowBase + srow0) * lda + k0 + skoff, ldsA0);
        if (srow1 < rowsValid) GLL16(A + (long)(rowBase + srow1) * lda + k0 + skoff, ldsA1);
        GLL16(Bp + (long)(n0 + srow0) * ldb + k0 + skoff, ldsB0);
        GLL16(Bp + (long)(n0 + srow1) * ldb + k0 + skoff, ldsB1);
        __syncthreads();
        short8 af[4], bfr[4];
        #pragma unroll
        for (int mi = 0; mi < 4; mi++)
            af[mi] = *(const short8*)(&As[(wm + mi * 16 + lrow) * 32 + quad * 8]);
        #pragma unroll
        for (int ni = 0; ni < 4; ni++)
            bfr[ni] = *(const short8*)(&Bs[(wn + ni * 16 + lrow) * 32 + quad * 8]);
        #pragma unroll
        for (int mi = 0; mi < 4; mi++)
            #pragma unroll
            for (int ni = 0; ni < 4; ni++)
                acc[mi][ni] = __builtin_amdgcn_mfma_f32_16x16x32_bf16(
                    af[mi], bfr[ni], acc[mi][ni], 0, 0, 0);
        __syncthreads();
    }

    #pragma unroll
    for (int mi = 0; mi < 4; mi++) {
        #pragma unroll
        for (int ni = 0; ni < 4; ni++) {
            #pragma unroll
            for (int r = 0; r < 4; r++) {
                int rl = wm + mi * 16 + quad * 4 + r;
                if (rl >= rowsValid) continue;
                int grow = rowBase + rl;
                int gcol = n0 + wn + ni * 16 + lrow;
                float v = acc[mi][ni][r];
                if (flags & GEMM_BIAS) v += bias[gcol];
                if (flags & GEMM_DOWN) {
                    int tok = perm[grow];
                    float* o = &outp[(long)tok * ldc + gcol];
                    *o = *o + v;   // owner-exclusive RMW (resid pre-stored by k_ode)
                } else {
                    if (flags & GEMM_WRITE) C[(long)grow * ldc + gcol] = v;
                    if (flags & GEMM_WRITEB) Cb[(long)grow * ldcb + gcol] = f2b(v);
                }
            }
        }
    }
}

// ---------------- ctrl_in GEMM: part[kc] = [o|vel] @ W_in (K-chunked) ------
__global__ __launch_bounds__(256) void k_ctrl_gemm(
    const bf16* __restrict__ A,      // ctrlA 2048 x 2048
    const bf16* __restrict__ Bt,     // ctrl_inT 64 x 2048
    float* __restrict__ part)        // [8][2048][64]
{
    __shared__ __align__(16) short As[128 * 32];
    __shared__ __align__(16) short Bs[64 * 32];
    int tid = threadIdx.x;
    int rowBase = blockIdx.x * 128;
    int kbeg = blockIdx.y * 256;
    int wave = tid >> 6, lane = tid & 63;
    int wm = wave * 32, lrow = lane & 15, quad = lane >> 4;
    int srow = lane >> 2, skoff = (lane & 3) * 8;

    floatx4 acc[2][4];
    #pragma unroll
    for (int i = 0; i < 2; i++)
        #pragma unroll
        for (int j = 0; j < 4; j++) acc[i][j] = (floatx4){0.f, 0.f, 0.f, 0.f};

    short* ldsA0 = As + (wave * 2) * 512;
    short* ldsA1 = As + (wave * 2 + 1) * 512;
    short* ldsB  = Bs + wave * 512;

    for (int k0 = kbeg; k0 < kbeg + 256; k0 += 32) {
        GLL16(A + (long)(rowBase + wave * 32 + srow) * 2048 + k0 + skoff, ldsA0);
        GLL16(A + (long)(rowBase + wave * 32 + 16 + srow) * 2048 + k0 + skoff, ldsA1);
        GLL16(Bt + (long)(wave * 16 + srow) * 2048 + k0 + skoff, ldsB);
        __syncthreads();
        short8 af[2], bfr[4];
        af[0] = *(const short8*)(&As[(wm + lrow) * 32 + quad * 8]);
        af[1] = *(const short8*)(&As[(wm + 16 + lrow) * 32 + quad * 8]);
        #pragma unroll
        for (int ni = 0; ni < 4; ni++)
            bfr[ni] = *(const short8*)(&Bs[(ni * 16 + lrow) * 32 + quad * 8]);
        #pragma unroll
        for (int mi = 0; mi < 2; mi++)
            #pragma unroll
            for (int ni = 0; ni < 4; ni++)
                acc[mi][ni] = __builtin_amdgcn_mfma_f32_16x16x32_bf16(
                    af[mi], bfr[ni], acc[mi][ni], 0, 0, 0);
        __syncthreads();
    }
    #pragma unroll
    for (int mi = 0; mi < 2; mi++)
        #pragma unroll
        for (int ni = 0; ni < 4; ni++)
            #pragma unroll
            for (int r = 0; r < 4; r++) {
                int grow = rowBase + wm + mi * 16 + quad * 4 + r;
                part[((long)blockIdx.y * N_TOK + grow) * 64 + ni * 16 + lrow] = acc[mi][ni][r];
            }
}

__global__ __launch_bounds__(256) void k_silu_ctrl(const float* __restrict__ part,
                                                   const float* __restrict__ b,
                                                   bf16* __restrict__ out) {
    int i = blockIdx.x * 256 + threadIdx.x;     // 2048*64
    float a = b[i & 63];
    #pragma unroll
    for (int kc = 0; kc < 8; kc++) a += part[(long)kc * (N_TOK * 64) + i];
    out[i] = f2b(a / (1.f + __expf(-a)));
}

// ---------------- qk norm + rope + split (fp32 in, bf16 out) ---------------
__global__ __launch_bounds__(256) void k_qkv_post(
    const float* __restrict__ qkv, const int* __restrict__ positions,
    const float* __restrict__ qnw, const float* __restrict__ knw,
    bf16* __restrict__ q, bf16* __restrict__ k, bf16* __restrict__ v)
{
    int n = blockIdx.x;
    int wave = threadIdx.x >> 6, lane = threadIdx.x & 63;
    float pos = (float)positions[n];
    int i = lane & 31;
    float invf = powf(10000.f, -((float)(2 * i)) / 64.f);
    float ang = pos * invf;
    float c = cosf(ang), s = sinf(ang);

    #pragma unroll
    for (int si = 0; si < 6; si++) {
        int slot = wave + si * 4;  // 0..23
        long base = (long)n * 1536 +
                    (slot < 16 ? slot * 64
                               : (slot < 20 ? 1024 + (slot - 16) * 64
                                            : 1280 + (slot - 20) * 64));
        float val = qkv[base + lane];
        if (slot < 20) {
            float ss = val * val;
            #pragma unroll
            for (int m = 1; m < 64; m <<= 1) ss += __shfl_xor(ss, m, 64);
            float r = rsqrtf(ss / 64.f + 1e-6f);
            float wn = (slot < 16 ? qnw[lane] : knw[lane]);
            float xn = val * r * wn;
            float partner = __shfl_xor(xn, 32, 64);
            float out = (lane < 32) ? (xn * c - partner * s) : (xn * c + partner * s);
            if (slot < 16) q[((long)n * NH + slot) * 64 + lane] = f2b(out);
            else           k[((long)n * NKV + (slot - 16)) * 64 + lane] = f2b(out);
        } else {
            v[((long)n * NKV + (slot - 20)) * 64 + lane] = f2b(val);
        }
    }
}

// ---------------- flash attention (bf16 in/out) ----------------
__global__ __launch_bounds__(256) void k_attn(
    const bf16* __restrict__ q, const bf16* __restrict__ k,
    const bf16* __restrict__ v, bf16* __restrict__ attn_out)
{
    const int h = blockIdx.y;
    const int qbase = blockIdx.x * 64;
    const int kvh = h >> 2;
    __shared__ __align__(16) short Qs[64 * 72];
    __shared__ __align__(16) short Ks[64 * 72];
    __shared__ __align__(16) short Vt[64 * 72];
    __shared__ __align__(16) short Ps[4 * 16 * 72];
    int tid = threadIdx.x, wave = tid >> 6, lane = tid & 63;
    int lrow = lane & 15, quad = lane >> 4;

    #pragma unroll
    for (int i = 0; i < 2; i++) {
        int lin = tid + i * 256;
        int r = lin >> 3, dc = (lin & 7) << 3;
        short8 vq = *(const short8*)(q + ((long)(qbase + r) * NH + h) * 64 + dc);
        *(short8*)&Qs[r * 72 + dc] = vq;
    }
    float m_i[4], l_i[4];
    floatx4 oacc[4];
    #pragma unroll
    for (int r = 0; r < 4; r++) { m_i[r] = -1e30f; l_i[r] = 0.f; }
    #pragma unroll
    for (int di = 0; di < 4; di++) oacc[di] = (floatx4){0.f, 0.f, 0.f, 0.f};
    const float scale = 0.125f;
    __syncthreads();

    for (int kt = 0; kt < N_TOK; kt += 64) {
        #pragma unroll
        for (int i = 0; i < 2; i++) {
            int lin = tid + i * 256;
            int r = lin >> 3, dc = (lin & 7) << 3;
            short8 k8 = *(const short8*)(k + ((long)(kt + r) * NKV + kvh) * 64 + dc);
            *(short8*)&Ks[r * 72 + dc] = k8;
            short8 v8 = *(const short8*)(v + ((long)(kt + r) * NKV + kvh) * 64 + dc);
            #pragma unroll
            for (int j = 0; j < 8; j++) Vt[(dc + j) * 72 + r] = ((short*)&v8)[j];
        }
        __syncthreads();

        short8 aq0 = *(const short8*)&Qs[(wave * 16 + lrow) * 72 + quad * 8];
        short8 aq1 = *(const short8*)&Qs[(wave * 16 + lrow) * 72 + 32 + quad * 8];
        floatx4 sv[4];
        #pragma unroll
        for (int kn = 0; kn < 4; kn++) {
            short8 b0 = *(const short8*)&Ks[(kn * 16 + lrow) * 72 + quad * 8];
            short8 b1 = *(const short8*)&Ks[(kn * 16 + lrow) * 72 + 32 + quad * 8];
            floatx4 t = (floatx4){0.f, 0.f, 0.f, 0.f};
            t = __builtin_amdgcn_mfma_f32_16x16x32_bf16(aq0, b0, t, 0, 0, 0);
            t = __builtin_amdgcn_mfma_f32_16x16x32_bf16(aq1, b1, t, 0, 0, 0);
            sv[kn] = t;
        }
        #pragma unroll
        for (int kn = 0; kn < 4; kn++)
            #pragma unroll
            for (int r = 0; r < 4; r++) sv[kn][r] *= scale;

        #pragma unroll
        for (int r = 0; r < 4; r++) {
            float mx = fmaxf(fmaxf(sv[0][r], sv[1][r]), fmaxf(sv[2][r], sv[3][r]));
            #pragma unroll
            for (int msk = 1; msk < 16; msk <<= 1) mx = fmaxf(mx, __shfl_xor(mx, msk, 64));
            float mnew = fmaxf(m_i[r], mx);
            float alpha = __expf(m_i[r] - mnew);
            m_i[r] = mnew;
            l_i[r] *= alpha;
            #pragma unroll
            for (int di = 0; di < 4; di++) oacc[di][r] *= alpha;
            float rowsum = 0.f;
            #pragma unroll
            for (int kn = 0; kn < 4; kn++) {
                float pp = __expf(sv[kn][r] - mnew);
                sv[kn][r] = pp;
                rowsum += pp;
            }
            #pragma unroll
            for (int msk = 1; msk < 16; msk <<= 1) rowsum += __shfl_xor(rowsum, msk, 64);
            l_i[r] += rowsum;
        }
        #pragma unroll
        for (int kn = 0; kn < 4; kn++)
            #pragma unroll
            for (int r = 0; r < 4; r++)
                Ps[(wave * 16 + quad * 4 + r) * 72 + kn * 16 + lrow] = f2s(sv[kn][r]);
        __syncthreads();

        short8 ap0 = *(const short8*)&Ps[(wave * 16 + lrow) * 72 + quad * 8];
        short8 ap1 = *(const short8*)&Ps[(wave * 16 + lrow) * 72 + 32 + quad * 8];
        #pragma unroll
        for (int di = 0; di < 4; di++) {
            short8 bv0 = *(const short8*)&Vt[(di * 16 + lrow) * 72 + quad * 8];
            short8 bv1 = *(const short8*)&Vt[(di * 16 + lrow) * 72 + 32 + quad * 8];
            oacc[di] = __builtin_amdgcn_mfma_f32_16x16x32_bf16(ap0, bv0, oacc[di], 0, 0, 0);
            oacc[di] = __builtin_amdgcn_mfma_f32_16x16x32_bf16(ap1, bv1, oacc[di], 0, 0, 0);
        }
        __syncthreads();
    }

    #pragma unroll
    for (int di = 0; di < 4; di++)
        #pragma unroll
        for (int r = 0; r < 4; r++) {
            float oval = oacc[di][r] / l_i[r];
            int n = qbase + wave * 16 + quad * 4 + r;
            attn_out[(long)n * DM + h * 64 + di * 16 + lrow] = f2b(oval);
        }
}

// ---------------- ODE + router + rmsnorm2 ----------------
__global__ __launch_bounds__(256) void k_ode(
    const float* __restrict__ co, const float* __restrict__ o_f,
    const float* __restrict__ velocity, const float* __restrict__ mu_f,
    const float* __restrict__ hidden_in,
    const float* __restrict__ mu_router_w, const int* __restrict__ token_ids,
    const float* __restrict__ ln2_w,
    float* __restrict__ out0, float* __restrict__ out_vnext,
    float* __restrict__ out_mu, bf16* __restrict__ x_bf,
    int* __restrict__ expert_id, int* __restrict__ counts)
{
    int n = blockIdx.x, tid = threadIdx.x;
    __shared__ float mu_s[DM];
    __shared__ float red2[32][8];

    #pragma unroll
    for (int i = 0; i < 4; i++) {
        int c = tid + i * 256;
        mu_s[c] = mu_f[(long)n * DM + c];
    }
    __syncthreads();

    {
        int e = tid & 7, kc = tid >> 3;
        float a = 0.f;
        #pragma unroll
        for (int kk = 0; kk < 32; kk++) {
            int k = kc * 32 + kk;
            a += mu_s[k] * mu_router_w[k * NE + e];
        }
        red2[kc][e] = a;
    }
    __syncthreads();
    if (tid == 0) {
        int bid = token_ids[n] & (NE - 1);
        float best = -1e30f; int bi = 0;
        for (int e = 0; e < NE; e++) {
            float lg = (e == bid ? 10.f : 0.f);
            for (int j = 0; j < 32; j++) lg += red2[j][e];
            if (lg > best) { best = lg; bi = e; }
        }
        expert_id[n] = bi;
        atomicAdd(&counts[bi], 1);
    }

    float ssq = 0.f;
    float h1v[4];
    #pragma unroll
    for (int i = 0; i < 4; i++) {
        int c = tid + i * 256;
        float coa = co[(long)n * 3072 + c];
        float cob = co[(long)n * 3072 + DM + c];
        float cog = co[(long)n * 3072 + 2 * DM + c];
        float alpha = 1.f / (1.f + __expf(-coa));
        float sp = (cob > 20.f) ? cob : log1pf(__expf(cob));
        float beta = fminf(sp, 2.0f);
        float gate = 1.f / (1.f + __expf(-cog));
        float ov = o_f[(long)n * DM + c];
        float vv = velocity[(long)n * DM + c];
        float err = ov - mu_s[c];
        float vn = fminf(fmaxf(alpha * vv - beta * err, -10.f), 10.f);
        float hn = ov + 0.1f * gate * vn;
        float h1 = hidden_in[(long)n * DM + c] + hn;
        h1v[i] = h1;
        ssq += h1 * h1;
        out_vnext[(long)n * DM + c] = vn;
        out_mu[(long)n * DM + c] = mu_s[c];
        out0[(long)n * DM + c] = h1;     // pre-MoE residual; down-GEMM adds y
    }
    float tot = blockReduceSum256(ssq);
    float rstd = rsqrtf(tot / (float)DM + 1e-6f);
    #pragma unroll
    for (int i = 0; i < 4; i++) {
        int c = tid + i * 256;
        x_bf[(long)n * DM + c] = f2b(h1v[i] * rstd * ln2_w[c]);
    }
}

// ---------------- MoE aux ----------------
__global__ void k_zero8(int* counts, int* fill) {
    if (threadIdx.x < NE) { counts[threadIdx.x] = 0; fill[threadIdx.x] = 0; }
}
__global__ void k_offsets(const int* counts, int* off) {
    if (threadIdx.x == 0) {
        int a = 0;
        for (int e = 0; e < NE; e++) { off[e] = a; a += counts[e]; }
        off[NE] = a;
    }
}
__global__ void k_scatter(const int* expert_id, const int* off, int* fill, int* perm) {
    int n = blockIdx.x * 256 + threadIdx.x;
    if (n < N_TOK) {
        int e = expert_id[n];
        int p = off[e] + atomicAdd(&fill[e], 1);
        perm[p] = n;
    }
}
__global__ __launch_bounds__(256) void k_gather(const int* __restrict__ perm,
                                                const bf16* __restrict__ x,
                                                bf16* __restrict__ xg) {
    int r = blockIdx.x;
    int tok = perm[r];
    ((int2*)(xg + (long)r * DM))[threadIdx.x] =
        ((const int2*)(x + (long)tok * DM))[threadIdx.x];
}
__global__ __launch_bounds__(256) void k_silumul(const bf16* __restrict__ gu,
                                                 bf16* __restrict__ mid) {
    long i = (long)blockIdx.x * 256 + threadIdx.x;   // over 2048*2048
    long r = i >> 11, c = i & 2047;
    float g = b2f(gu[r * 4096 + c]);
    float u = b2f(gu[r * 4096 + 2048 + c]);
    mid[i] = f2b(g / (1.f + __expf(-g)) * u);
}

// ---------------- launcher ----------------
extern "C" void kernel_launch(void* const* d_in, const int* in_sizes, int n_in,
                              void* d_out, int out_size, void* d_ws, size_t ws_size,
                              hipStream_t stream) {
    (void)in_sizes; (void)n_in; (void)out_size; (void)ws_size;
    const float* hidden     = (const float*)d_in[0];
    const int*   positions  = (const int*)d_in[1];
    const float* velocity   = (const float*)d_in[2];
    const int*   token_ids  = (const int*)d_in[3];
    const float* mu_prev    = (const float*)d_in[4];
    const float* ln1_w      = (const float*)d_in[5];
    const float* ln2_w      = (const float*)d_in[6];
    const float* wq         = (const float*)d_in[7];
    const float* wk         = (const float*)d_in[8];
    const float* wv         = (const float*)d_in[9];
    const float* wo         = (const float*)d_in[10];
    const float* w_mu_q     = (const float*)d_in[11];
    const float* w_mu_k     = (const float*)d_in[12];
    const float* w_mu_v     = (const float*)d_in[13];
    const float* qnorm_w    = (const float*)d_in[14];
    const float* knorm_w    = (const float*)d_in[15];
    const float* dyn_mu     = (const float*)d_in[16];
    const float* dyn_proj   = (const float*)d_in[17];
    const float* ctrl_in_w  = (const float*)d_in[18];
    const float* ctrl_in_b  = (const float*)d_in[19];
    const float* ctrl_out_w = (const float*)d_in[20];
    const float* ctrl_out_b = (const float*)d_in[21];
    const float* mu_router  = (const float*)d_in[22];
    const float* w_gate     = (const float*)d_in[23];
    const float* w_up       = (const float*)d_in[24];
    const float* w_down     = (const float*)d_in[25];

    float* out0 = (float*)d_out;
    float* out1 = out0 + (long)N_TOK * DM;
    float* out2 = out1 + (long)N_TOK * DM;

    char* p = (char*)d_ws;
    auto alloc = [&](size_t bytes) -> void* {
        void* r = (void*)p;
        p += (bytes + 255) & ~(size_t)255;
        return r;
    };
    // bf16 transposed weights
    bf16* WqkvT   = (bf16*)alloc((long)1536 * 2048 * 2);
    bf16* woT     = (bf16*)alloc((long)1024 * 1024 * 2);
    bf16* dynT    = (bf16*)alloc((long)1024 * 1024 * 2);
    bf16* ctrlinT = (bf16*)alloc((long)64 * 2048 * 2);
    bf16* ctrloutT= (bf16*)alloc((long)3072 * 64 * 2);
    bf16* gupT    = (bf16*)alloc((long)NE * 4096 * 1024 * 2);
    bf16* downT   = (bf16*)alloc((long)NE * 1024 * 2048 * 2);
    // activations
    bf16*  catA   = (bf16*)alloc((long)N_TOK * 2048 * 2);  // [h|mu_prev]; attn_bf alias
    bf16*  ctrlA  = (bf16*)alloc((long)N_TOK * 2048 * 2);  // [o_bf|vel_bf]
    float* qkv_f  = (float*)alloc((long)N_TOK * 1536 * 4); // x_bf/xg_bf/part alias
    bf16*  q_bf   = (bf16*)alloc((long)N_TOK * NH * DH * 2);
    bf16*  k_bf   = (bf16*)alloc((long)N_TOK * NKV * DH * 2);
    bf16*  v_bf   = (bf16*)alloc((long)N_TOK * NKV * DH * 2);
    float* o_f    = (float*)alloc((long)N_TOK * DM * 4);   // mid_bf alias
    float* mu_f   = (float*)alloc((long)N_TOK * DM * 4);
    float* coGu   = (float*)alloc((long)N_TOK * 3072 * 4); // co fp32; later gu_bf
    bf16*  ctrlbf = (bf16*)alloc((long)N_TOK * CH * 2);
    int*   expert_id = (int*)alloc(N_TOK * 4);
    int*   perm      = (int*)alloc(N_TOK * 4);
    int*   counts    = (int*)alloc(64 * 4);
    int*   fill      = (int*)alloc(64 * 4);
    int*   offs      = (int*)alloc(64 * 4);

    bf16*  attn_bf = catA;                                  // catA dead after QKV gemm
    bf16*  x_bf    = (bf16*)qkv_f;                          // qkv dead after qkv_post
    bf16*  xg_bf   = (bf16*)qkv_f + (long)N_TOK * DM;
    float* part    = (float*)((bf16*)qkv_f + (long)2 * N_TOK * DM);  // 8*2048*64 fp32
    float* co_f    = coGu;
    bf16*  gu_bf   = (bf16*)coGu;                           // co dead after k_ode
    bf16*  mid_bf  = (bf16*)o_f;                            // o_f dead after k_ode

    dim3 blk(256);
    k_zero8<<<1, 64, 0, stream>>>(counts, fill);

    // ---- weight transposes (fp32 KxN -> bf16 NxK) ----
    k_transpose<<<dim3(16,16,1), blk, 0, stream>>>(wq, 0, 1024, WqkvT, 0, 2048);
    k_transpose<<<dim3(4,16,1),  blk, 0, stream>>>(wk, 0, 256,  WqkvT + (long)1024*2048, 0, 2048);
    k_transpose<<<dim3(4,16,1),  blk, 0, stream>>>(wv, 0, 256,  WqkvT + (long)1280*2048, 0, 2048);
    k_transpose<<<dim3(16,16,1), blk, 0, stream>>>(w_mu_q, 0, 1024, WqkvT + 1024, 0, 2048);
    k_transpose<<<dim3(4,16,1),  blk, 0, stream>>>(w_mu_k, 0, 256,  WqkvT + (long)1024*2048 + 1024, 0, 2048);
    k_transpose<<<dim3(4,16,1),  blk, 0, stream>>>(w_mu_v, 0, 256,  WqkvT + (long)1280*2048 + 1024, 0, 2048);
    k_transpose<<<dim3(16,16,1), blk, 0, stream>>>(wo, 0, 1024, woT, 0, 1024);
    k_transpose<<<dim3(16,16,1), blk, 0, stream>>>(dyn_proj, 0, 1024, dynT, 0, 1024);
    k_transpose<<<dim3(1,32,1),  blk, 0, stream>>>(ctrl_in_w, 0, 64, ctrlinT, 0, 2048);
    k_transpose<<<dim3(48,1,1),  blk, 0, stream>>>(ctrl_out_w, 0, 3072, ctrloutT, 0, 64);
    k_transpose<<<dim3(32,16,NE), blk, 0, stream>>>(w_gate, (long)1024*2048, 2048,
        gupT, (long)4096*1024, 1024);
    k_transpose<<<dim3(32,16,NE), blk, 0, stream>>>(w_up, (long)1024*2048, 2048,
        gupT + (long)2048*1024, (long)4096*1024, 1024);
    k_transpose<<<dim3(16,32,NE), blk, 0, stream>>>(w_down, (long)2048*1024, 1024,
        downT, (long)1024*2048, 2048);

    // ---- activation preps ----
    k_cvt<<<N_TOK, blk, 0, stream>>>(mu_prev, catA + 1024);
    k_cvt<<<N_TOK, blk, 0, stream>>>(velocity, ctrlA + 1024);
    k_rmsnorm<<<N_TOK, blk, 0, stream>>>(hidden, ln1_w, catA);

    // ---- QKV: qkv = [h|mu] @ [Wqkv; Wmu]  (M=2048,N=1536,K=2048) ----
    k_gemm<<<dim3(12,16,1), blk, 0, stream>>>(catA, 2048, WqkvT, 2048, 0,
        qkv_f, 1536, nullptr, nullptr, 0, 2048, GEMM_WRITE, nullptr, nullptr, nullptr);

    k_qkv_post<<<N_TOK, blk, 0, stream>>>(qkv_f, positions, qnorm_w, knorm_w, q_bf, k_bf, v_bf);
    k_attn<<<dim3(32,16,1), blk, 0, stream>>>(q_bf, k_bf, v_bf, attn_bf);

    // ---- o = attn @ wo  (fp32 o_f + bf16 into ctrlA[:,0:1024]) ----
    k_gemm<<<dim3(8,16,1), blk, 0, stream>>>(attn_bf, 1024, woT, 1024, 0,
        o_f, 1024, nullptr, ctrlA, 2048, 1024, GEMM_WRITE | GEMM_WRITEB,
        nullptr, nullptr, nullptr);
    // ---- mu = dyn_mu + o @ dyn_proj ----
    k_gemm<<<dim3(8,16,1), blk, 0, stream>>>(ctrlA, 2048, dynT, 1024, 0,
        mu_f, 1024, dyn_mu, nullptr, 0, 1024, GEMM_WRITE | GEMM_BIAS,
        nullptr, nullptr, nullptr);

    // ---- ctrl chain ----
    k_ctrl_gemm<<<dim3(16,8,1), blk, 0, stream>>>(ctrlA, ctrlinT, part);
    k_silu_ctrl<<<(N_TOK * CH) / 256, blk, 0, stream>>>(part, ctrl_in_b, ctrlbf);
    k_gemm<<<dim3(24,16,1), blk, 0, stream>>>(ctrlbf, 64, ctrloutT, 64, 0,
        co_f, 3072, ctrl_out_b, nullptr, 0, 64, GEMM_WRITE | GEMM_BIAS,
        nullptr, nullptr, nullptr);

    k_ode<<<N_TOK, blk, 0, stream>>>(co_f, o_f, velocity, mu_f, hidden,
        mu_router, token_ids, ln2_w, out0, out1, out2, x_bf, expert_id, counts);

    k_offsets<<<1, 64, 0, stream>>>(counts, offs);
    k_scatter<<<NE, blk, 0, stream>>>(expert_id, offs, fill, perm);
    k_gather<<<N_TOK, blk, 0, stream>>>(perm, x_bf, xg_bf);

    // ---- MoE: [gate|up] combined (N=4096), then silu*mul, then down ----
    k_gemm<<<dim3(32,16,NE), blk, 0, stream>>>(xg_bf, 1024, gupT, 1024, (long)4096*1024,
        nullptr, 0, nullptr, gu_bf, 4096, 1024, GEMM_WRITEB, offs, nullptr, nullptr);
    k_silumul<<<(N_TOK * FF) / 256, blk, 0, stream>>>(gu_bf, mid_bf);
    k_gemm<<<dim3(8,16,NE), blk, 0, stream>>>(mid_bf, 2048, downT, 2048, (long)1024*2048,
        nullptr, 1024, nullptr, nullptr, 0, 2048, GEMM_DOWN, offs, perm, out0);
}

// Round 6
// 737.494 us; speedup vs baseline: 2.9231x; 1.0380x over previous
//
#include <hip/hip_runtime.h>
#include <hip/hip_bf16.h>
#include <math.h>

typedef __hip_bfloat16 bf16;
typedef __attribute__((ext_vector_type(8))) short short8;
typedef __attribute__((ext_vector_type(4))) float floatx4;

#define N_TOK 2048
#define DM    1024
#define NH    16
#define NKV   4
#define DH    64
#define NE    8
#define FF    2048
#define CH    64

__device__ __forceinline__ float b2f(bf16 x) { return __bfloat162float(x); }
__device__ __forceinline__ bf16  f2b(float x) { return __float2bfloat16(x); }
__device__ __forceinline__ short f2s(float x) { bf16 t = __float2bfloat16(x); return *(short*)&t; }

// async global->LDS, 16B per lane; LDS dest = wave-uniform base + lane*16
#define GLL16(g, l) __builtin_amdgcn_global_load_lds( \
    (const __attribute__((address_space(1))) void*)(g), \
    (__attribute__((address_space(3))) void*)(l), 16, 0, 0)

__device__ __forceinline__ float blockReduceSum256(float v) {
    __shared__ float tmp[4];
    #pragma unroll
    for (int m = 1; m < 64; m <<= 1) v += __shfl_xor(v, m, 64);
    if ((threadIdx.x & 63) == 0) tmp[threadIdx.x >> 6] = v;
    __syncthreads();
    float r = tmp[0] + tmp[1] + tmp[2] + tmp[3];
    __syncthreads();
    return r;
}

// ---------------- transpose fp32 KxN -> bf16 NxK ----------------
__global__ __launch_bounds__(256) void k_transpose(
    const float* __restrict__ src, long sstrideE, int sN,
    bf16* __restrict__ dst, long dstrideE, int ldk)
{
    __shared__ float tile[64][65];
    const float* s = src + (long)blockIdx.z * sstrideE;
    bf16* d = dst + (long)blockIdx.z * dstrideE;
    int n0 = blockIdx.x * 64, k0 = blockIdx.y * 64;
    int tid = threadIdx.x;
    int c = tid & 63, r4 = tid >> 6;
    #pragma unroll
    for (int i = 0; i < 16; i++) {
        int r = i * 4 + r4;
        tile[r][c] = s[(long)(k0 + r) * sN + n0 + c];
    }
    __syncthreads();
    int c2 = (tid & 31) * 2, rr = tid >> 5;
    #pragma unroll
    for (int i = 0; i < 8; i++) {
        int r = i * 8 + rr;
        short2 o;
        o.x = f2s(tile[c2][r]);
        o.y = f2s(tile[c2 + 1][r]);
        *(short2*)(d + (long)(n0 + r) * ldk + k0 + c2) = o;
    }
}

// ---------------- fused: rmsnorm(hidden)->catA[:,0:1024], cvt mu/vel -------
__global__ __launch_bounds__(256) void k_prep(
    const float* __restrict__ hidden, const float* __restrict__ ln1_w,
    const float* __restrict__ mu_prev, const float* __restrict__ velocity,
    bf16* __restrict__ catA, bf16* __restrict__ ctrlA)
{
    int n = blockIdx.x, tid = threadIdx.x;
    float ss = 0.f, vals[4];
    #pragma unroll
    for (int i = 0; i < 4; i++) {
        int c = tid + i * 256;
        vals[i] = hidden[(long)n * DM + c];
        ss += vals[i] * vals[i];
        catA[(long)n * 2048 + 1024 + c] = f2b(mu_prev[(long)n * DM + c]);
        ctrlA[(long)n * 2048 + 1024 + c] = f2b(velocity[(long)n * DM + c]);
    }
    float tot = blockReduceSum256(ss);
    float r = rsqrtf(tot / (float)DM + 1e-6f);
    #pragma unroll
    for (int i = 0; i < 4; i++) {
        int c = tid + i * 256;
        catA[(long)n * 2048 + c] = f2b(vals[i] * r * ln1_w[c]);
    }
}

// ---------------- generic 128x128 MFMA GEMM, bf16 A (MxK) x bf16 B^T (NxK) -
#define GEMM_WRITE  1
#define GEMM_BIAS   2
#define GEMM_WRITEB 4
#define GEMM_DOWN   8

__global__ __launch_bounds__(256) void k_gemm(
    const bf16* __restrict__ A, int lda,
    const bf16* __restrict__ Bt, int ldb, long strideBe,
    float* __restrict__ C, int ldc,
    const float* __restrict__ bias,
    bf16* __restrict__ Cb, int ldcb,
    int K, int flags,
    const int* __restrict__ grp_off,
    const int* __restrict__ perm,
    float* __restrict__ outp)
{
    __shared__ __align__(16) short As[128 * 32];
    __shared__ __align__(16) short Bs[128 * 32];
    int tid = threadIdx.x;
    int e = blockIdx.z;
    int rowBase, rowsValid;
    const bf16* Bp = Bt;
    if (grp_off) {
        int r0 = grp_off[e], r1 = grp_off[e + 1];
        int rt = blockIdx.y * 128;
        rowsValid = (r1 - r0) - rt;
        if (rowsValid <= 0) return;
        if (rowsValid > 128) rowsValid = 128;
        rowBase = r0 + rt;
        Bp = Bt + (long)e * strideBe;
    } else {
        rowBase = blockIdx.y * 128;
        rowsValid = 128;
    }
    int n0 = blockIdx.x * 128;

    floatx4 acc[4][4];
    #pragma unroll
    for (int i = 0; i < 4; i++)
        #pragma unroll
        for (int j = 0; j < 4; j++) acc[i][j] = (floatx4){0.f, 0.f, 0.f, 0.f};

    int wave = tid >> 6, lane = tid & 63;
    int wm = (wave >> 1) * 64, wn = (wave & 1) * 64;
    int lrow = lane & 15, quad = lane >> 4;

    int c0 = wave * 2;
    int srow0 = c0 * 16 + (lane >> 2);
    int srow1 = (c0 + 1) * 16 + (lane >> 2);
    int skoff = (lane & 3) * 8;
    short* ldsA0 = As + c0 * 512;
    short* ldsA1 = As + (c0 + 1) * 512;
    short* ldsB0 = Bs + c0 * 512;
    short* ldsB1 = Bs + (c0 + 1) * 512;

    for (int k0 = 0; k0 < K; k0 += 32) {
        if (srow0 < rowsValid) GLL16(A + (long)(rowBase + srow0) * lda + k0 + skoff, ldsA0);
        if (srow1 < rowsValid) GLL16(A + (long)(rowBase + srow1) * lda + k0 + skoff, ldsA1);
        GLL16(Bp + (long)(n0 + srow0) * ldb + k0 + skoff, ldsB0);
        GLL16(Bp + (long)(n0 + srow1) * ldb + k0 + skoff, ldsB1);
        __syncthreads();
        short8 af[4], bfr[4];
        #pragma unroll
        for (int mi = 0; mi < 4; mi++)
            af[mi] = *(const short8*)(&As[(wm + mi * 16 + lrow) * 32 + quad * 8]);
        #pragma unroll
        for (int ni = 0; ni < 4; ni++)
            bfr[ni] = *(const short8*)(&Bs[(wn + ni * 16 + lrow) * 32 + quad * 8]);
        #pragma unroll
        for (int mi = 0; mi < 4; mi++)
            #pragma unroll
            for (int ni = 0; ni < 4; ni++)
                acc[mi][ni] = __builtin_amdgcn_mfma_f32_16x16x32_bf16(
                    af[mi], bfr[ni], acc[mi][ni], 0, 0, 0);
        __syncthreads();
    }

    #pragma unroll
    for (int mi = 0; mi < 4; mi++) {
        #pragma unroll
        for (int ni = 0; ni < 4; ni++) {
            #pragma unroll
            for (int r = 0; r < 4; r++) {
                int rl = wm + mi * 16 + quad * 4 + r;
                if (rl >= rowsValid) continue;
                int grow = rowBase + rl;
                int gcol = n0 + wn + ni * 16 + lrow;
                float v = acc[mi][ni][r];
                if (flags & GEMM_BIAS) v += bias[gcol];
                if (flags & GEMM_DOWN) {
                    int tok = perm[grow];
                    float* o = &outp[(long)tok * ldc + gcol];
                    *o = *o + v;   // owner-exclusive RMW (resid pre-stored by k_ode)
                } else {
                    if (flags & GEMM_WRITE) C[(long)grow * ldc + gcol] = v;
                    if (flags & GEMM_WRITEB) Cb[(long)grow * ldcb + gcol] = f2b(v);
                }
            }
        }
    }
}

// ---------------- ctrl_in GEMM: part[kc] = [o|vel] @ W_in (K-chunked) ------
__global__ __launch_bounds__(256) void k_ctrl_gemm(
    const bf16* __restrict__ A,      // ctrlA 2048 x 2048
    const bf16* __restrict__ Bt,     // ctrl_inT 64 x 2048
    float* __restrict__ part)        // [8][2048][64]
{
    __shared__ __align__(16) short As[128 * 32];
    __shared__ __align__(16) short Bs[64 * 32];
    int tid = threadIdx.x;
    int rowBase = blockIdx.x * 128;
    int kbeg = blockIdx.y * 256;
    int wave = tid >> 6, lane = tid & 63;
    int wm = wave * 32, lrow = lane & 15, quad = lane >> 4;
    int srow = lane >> 2, skoff = (lane & 3) * 8;

    floatx4 acc[2][4];
    #pragma unroll
    for (int i = 0; i < 2; i++)
        #pragma unroll
        for (int j = 0; j < 4; j++) acc[i][j] = (floatx4){0.f, 0.f, 0.f, 0.f};

    short* ldsA0 = As + (wave * 2) * 512;
    short* ldsA1 = As + (wave * 2 + 1) * 512;
    short* ldsB  = Bs + wave * 512;

    for (int k0 = kbeg; k0 < kbeg + 256; k0 += 32) {
        GLL16(A + (long)(rowBase + wave * 32 + srow) * 2048 + k0 + skoff, ldsA0);
        GLL16(A + (long)(rowBase + wave * 32 + 16 + srow) * 2048 + k0 + skoff, ldsA1);
        GLL16(Bt + (long)(wave * 16 + srow) * 2048 + k0 + skoff, ldsB);
        __syncthreads();
        short8 af[2], bfr[4];
        af[0] = *(const short8*)(&As[(wm + lrow) * 32 + quad * 8]);
        af[1] = *(const short8*)(&As[(wm + 16 + lrow) * 32 + quad * 8]);
        #pragma unroll
        for (int ni = 0; ni < 4; ni++)
            bfr[ni] = *(const short8*)(&Bs[(ni * 16 + lrow) * 32 + quad * 8]);
        #pragma unroll
        for (int mi = 0; mi < 2; mi++)
            #pragma unroll
            for (int ni = 0; ni < 4; ni++)
                acc[mi][ni] = __builtin_amdgcn_mfma_f32_16x16x32_bf16(
                    af[mi], bfr[ni], acc[mi][ni], 0, 0, 0);
        __syncthreads();
    }
    #pragma unroll
    for (int mi = 0; mi < 2; mi++)
        #pragma unroll
        for (int ni = 0; ni < 4; ni++)
            #pragma unroll
            for (int r = 0; r < 4; r++) {
                int grow = rowBase + wm + mi * 16 + quad * 4 + r;
                part[((long)blockIdx.y * N_TOK + grow) * 64 + ni * 16 + lrow] = acc[mi][ni][r];
            }
}

__global__ __launch_bounds__(256) void k_silu_ctrl(const float* __restrict__ part,
                                                   const float* __restrict__ b,
                                                   bf16* __restrict__ out) {
    int i = blockIdx.x * 256 + threadIdx.x;     // 2048*64
    float a = b[i & 63];
    #pragma unroll
    for (int kc = 0; kc < 8; kc++) a += part[(long)kc * (N_TOK * 64) + i];
    out[i] = f2b(a / (1.f + __expf(-a)));
}

// ---------------- qk norm + rope + split (fp32 in, bf16 out) ---------------
__global__ __launch_bounds__(256) void k_qkv_post(
    const float* __restrict__ qkv, const int* __restrict__ positions,
    const float* __restrict__ qnw, const float* __restrict__ knw,
    bf16* __restrict__ q, bf16* __restrict__ k, bf16* __restrict__ v)
{
    int n = blockIdx.x;
    int wave = threadIdx.x >> 6, lane = threadIdx.x & 63;
    float pos = (float)positions[n];
    int i = lane & 31;
    // theta^(-2i/64) = 2^(-2i/64 * log2(10000))
    float invf = exp2f(-(float)(2 * i) * (13.287712379549449f / 64.f));
    float ang = pos * invf;
    float c = cosf(ang), s = sinf(ang);

    #pragma unroll
    for (int si = 0; si < 6; si++) {
        int slot = wave + si * 4;  // 0..23
        long base = (long)n * 1536 +
                    (slot < 16 ? slot * 64
                               : (slot < 20 ? 1024 + (slot - 16) * 64
                                            : 1280 + (slot - 20) * 64));
        float val = qkv[base + lane];
        if (slot < 20) {
            float ss = val * val;
            #pragma unroll
            for (int m = 1; m < 64; m <<= 1) ss += __shfl_xor(ss, m, 64);
            float r = rsqrtf(ss / 64.f + 1e-6f);
            float wn = (slot < 16 ? qnw[lane] : knw[lane]);
            float xn = val * r * wn;
            float partner = __shfl_xor(xn, 32, 64);
            float out = (lane < 32) ? (xn * c - partner * s) : (xn * c + partner * s);
            if (slot < 16) q[((long)n * NH + slot) * 64 + lane] = f2b(out);
            else           k[((long)n * NKV + (slot - 16)) * 64 + lane] = f2b(out);
        } else {
            v[((long)n * NKV + (slot - 20)) * 64 + lane] = f2b(val);
        }
    }
}

// ---------------- V transpose: v[n][kv][d] -> vt[kv*64+d][n] ---------------
__global__ __launch_bounds__(256) void k_vt(const bf16* __restrict__ v,
                                            bf16* __restrict__ vt) {
    __shared__ short tile[64][65];
    int kv = blockIdx.z, n0 = blockIdx.x * 64;
    int tid = threadIdx.x;
    int c = tid & 63, r4 = tid >> 6;
    const short* vs = (const short*)v;
    #pragma unroll
    for (int i = 0; i < 16; i++) {
        int r = i * 4 + r4;
        tile[r][c] = vs[(long)(n0 + r) * 256 + kv * 64 + c];
    }
    __syncthreads();
    #pragma unroll
    for (int i = 0; i < 16; i++) {
        int d = i * 4 + r4;
        ((short*)vt)[(long)(kv * 64 + d) * 2048 + n0 + c] = tile[c][d];
    }
}

// ---------------- flash attention, KV-split (partials) ----------------
__global__ __launch_bounds__(256) void k_attn(
    const bf16* __restrict__ q, const bf16* __restrict__ k,
    const bf16* __restrict__ vt,
    float* __restrict__ opart, float2* __restrict__ ml)
{
    const int h = blockIdx.y;
    const int qbase = blockIdx.x * 64;
    const int z = blockIdx.z;
    const int kvh = h >> 2;
    __shared__ __align__(16) short Qs[64 * 72];
    __shared__ __align__(16) short Ks[64 * 72];
    __shared__ __align__(16) short Vt[64 * 72];
    __shared__ __align__(16) short Ps[4 * 16 * 72];
    int tid = threadIdx.x, wave = tid >> 6, lane = tid & 63;
    int lrow = lane & 15, quad = lane >> 4;

    #pragma unroll
    for (int i = 0; i < 2; i++) {
        int lin = tid + i * 256;
        int r = lin >> 3, dc = (lin & 7) << 3;
        short8 vq = *(const short8*)(q + ((long)(qbase + r) * NH + h) * 64 + dc);
        *(short8*)&Qs[r * 72 + dc] = vq;
    }
    float m_i[4], l_i[4];
    floatx4 oacc[4];
    #pragma unroll
    for (int r = 0; r < 4; r++) { m_i[r] = -1e30f; l_i[r] = 0.f; }
    #pragma unroll
    for (int di = 0; di < 4; di++) oacc[di] = (floatx4){0.f, 0.f, 0.f, 0.f};
    const float scale = 0.125f;
    __syncthreads();

    const int kt0 = z * (N_TOK / 2);
    for (int kt = kt0; kt < kt0 + N_TOK / 2; kt += 64) {
        #pragma unroll
        for (int i = 0; i < 2; i++) {
            int lin = tid + i * 256;
            int r = lin >> 3, dc = (lin & 7) << 3;
            short8 k8 = *(const short8*)(k + ((long)(kt + r) * NKV + kvh) * 64 + dc);
            *(short8*)&Ks[r * 72 + dc] = k8;
            // Vt tile: rows are d, cols are kv-pos (vectorized, conflict-light)
            short8 v8 = *(const short8*)(vt + (long)(kvh * 64 + r) * 2048 + kt + dc);
            *(short8*)&Vt[r * 72 + dc] = v8;
        }
        __syncthreads();

        short8 aq0 = *(const short8*)&Qs[(wave * 16 + lrow) * 72 + quad * 8];
        short8 aq1 = *(const short8*)&Qs[(wave * 16 + lrow) * 72 + 32 + quad * 8];
        floatx4 sv[4];
        #pragma unroll
        for (int kn = 0; kn < 4; kn++) {
            short8 b0 = *(const short8*)&Ks[(kn * 16 + lrow) * 72 + quad * 8];
            short8 b1 = *(const short8*)&Ks[(kn * 16 + lrow) * 72 + 32 + quad * 8];
            floatx4 t = (floatx4){0.f, 0.f, 0.f, 0.f};
            t = __builtin_amdgcn_mfma_f32_16x16x32_bf16(aq0, b0, t, 0, 0, 0);
            t = __builtin_amdgcn_mfma_f32_16x16x32_bf16(aq1, b1, t, 0, 0, 0);
            sv[kn] = t;
        }
        #pragma unroll
        for (int kn = 0; kn < 4; kn++)
            #pragma unroll
            for (int r = 0; r < 4; r++) sv[kn][r] *= scale;

        #pragma unroll
        for (int r = 0; r < 4; r++) {
            float mx = fmaxf(fmaxf(sv[0][r], sv[1][r]), fmaxf(sv[2][r], sv[3][r]));
            #pragma unroll
            for (int msk = 1; msk < 16; msk <<= 1) mx = fmaxf(mx, __shfl_xor(mx, msk, 64));
            float mnew = fmaxf(m_i[r], mx);
            float alpha = __expf(m_i[r] - mnew);
            m_i[r] = mnew;
            l_i[r] *= alpha;
            #pragma unroll
            for (int di = 0; di < 4; di++) oacc[di][r] *= alpha;
            float rowsum = 0.f;
            #pragma unroll
            for (int kn = 0; kn < 4; kn++) {
                float pp = __expf(sv[kn][r] - mnew);
                sv[kn][r] = pp;
                rowsum += pp;
            }
            #pragma unroll
            for (int msk = 1; msk < 16; msk <<= 1) rowsum += __shfl_xor(rowsum, msk, 64);
            l_i[r] += rowsum;
        }
        #pragma unroll
        for (int kn = 0; kn < 4; kn++)
            #pragma unroll
            for (int r = 0; r < 4; r++)
                Ps[(wave * 16 + quad * 4 + r) * 72 + kn * 16 + lrow] = f2s(sv[kn][r]);
        __syncthreads();

        short8 ap0 = *(const short8*)&Ps[(wave * 16 + lrow) * 72 + quad * 8];
        short8 ap1 = *(const short8*)&Ps[(wave * 16 + lrow) * 72 + 32 + quad * 8];
        #pragma unroll
        for (int di = 0; di < 4; di++) {
            short8 bv0 = *(const short8*)&Vt[(di * 16 + lrow) * 72 + quad * 8];
            short8 bv1 = *(const short8*)&Vt[(di * 16 + lrow) * 72 + 32 + quad * 8];
            oacc[di] = __builtin_amdgcn_mfma_f32_16x16x32_bf16(ap0, bv0, oacc[di], 0, 0, 0);
            oacc[di] = __builtin_amdgcn_mfma_f32_16x16x32_bf16(ap1, bv1, oacc[di], 0, 0, 0);
        }
        __syncthreads();
    }

    #pragma unroll
    for (int di = 0; di < 4; di++)
        #pragma unroll
        for (int r = 0; r < 4; r++) {
            int n = qbase + wave * 16 + quad * 4 + r;
            opart[((long)z * N_TOK + n) * DM + h * 64 + di * 16 + lrow] = oacc[di][r];
        }
    if (lrow == 0) {
        #pragma unroll
        for (int r = 0; r < 4; r++) {
            int n = qbase + wave * 16 + quad * 4 + r;
            ml[(long)(z * NH + h) * N_TOK + n] = make_float2(m_i[r], l_i[r]);
        }
    }
}

// ---------------- merge KV-split partials -> attn_out bf16 ----------------
__global__ __launch_bounds__(256) void k_attn_merge(
    const float* __restrict__ opart, const float2* __restrict__ ml,
    bf16* __restrict__ attn_out)
{
    int n = blockIdx.x, tid = threadIdx.x;
    __shared__ float2 sml[2][NH];
    if (tid < 32) {
        int z = tid >> 4, hh = tid & 15;
        sml[z][hh] = ml[(long)(z * NH + hh) * N_TOK + n];
    }
    __syncthreads();
    #pragma unroll
    for (int i = 0; i < 4; i++) {
        int c = tid + i * 256;
        int h = c >> 6;
        float2 a = sml[0][h], b = sml[1][h];
        float M = fmaxf(a.x, b.x);
        float w0 = __expf(a.x - M), w1 = __expf(b.x - M);
        float num = w0 * opart[(long)n * DM + c] +
                    w1 * opart[((long)N_TOK + n) * DM + c];
        float den = w0 * a.y + w1 * b.y;
        attn_out[(long)n * DM + c] = f2b(num / den);
    }
}

// ---------------- ODE + router + rmsnorm2 ----------------
__global__ __launch_bounds__(256) void k_ode(
    const float* __restrict__ co, const float* __restrict__ o_f,
    const float* __restrict__ velocity, const float* __restrict__ mu_f,
    const float* __restrict__ hidden_in,
    const float* __restrict__ mu_router_w, const int* __restrict__ token_ids,
    const float* __restrict__ ln2_w,
    float* __restrict__ out0, float* __restrict__ out_vnext,
    float* __restrict__ out_mu, bf16* __restrict__ x_bf,
    int* __restrict__ expert_id, int* __restrict__ counts)
{
    int n = blockIdx.x, tid = threadIdx.x;
    __shared__ float mu_s[DM];
    __shared__ float red2[32][8];

    #pragma unroll
    for (int i = 0; i < 4; i++) {
        int c = tid + i * 256;
        mu_s[c] = mu_f[(long)n * DM + c];
    }
    __syncthreads();

    {
        int e = tid & 7, kc = tid >> 3;
        float a = 0.f;
        #pragma unroll
        for (int kk = 0; kk < 32; kk++) {
            int k = kc * 32 + kk;
            a += mu_s[k] * mu_router_w[k * NE + e];
        }
        red2[kc][e] = a;
    }
    __syncthreads();
    if (tid == 0) {
        int bid = token_ids[n] & (NE - 1);
        float best = -1e30f; int bi = 0;
        for (int e = 0; e < NE; e++) {
            float lg = (e == bid ? 10.f : 0.f);
            for (int j = 0; j < 32; j++) lg += red2[j][e];
            if (lg > best) { best = lg; bi = e; }
        }
        expert_id[n] = bi;
        atomicAdd(&counts[bi], 1);
    }

    float ssq = 0.f;
    float h1v[4];
    #pragma unroll
    for (int i = 0; i < 4; i++) {
        int c = tid + i * 256;
        float coa = co[(long)n * 3072 + c];
        float cob = co[(long)n * 3072 + DM + c];
        float cog = co[(long)n * 3072 + 2 * DM + c];
        float alpha = 1.f / (1.f + __expf(-coa));
        float sp = (cob > 20.f) ? cob : log1pf(__expf(cob));
        float beta = fminf(sp, 2.0f);
        float gate = 1.f / (1.f + __expf(-cog));
        float ov = o_f[(long)n * DM + c];
        float vv = velocity[(long)n * DM + c];
        float err = ov - mu_s[c];
        float vn = fminf(fmaxf(alpha * vv - beta * err, -10.f), 10.f);
        float hn = ov + 0.1f * gate * vn;
        float h1 = hidden_in[(long)n * DM + c] + hn;
        h1v[i] = h1;
        ssq += h1 * h1;
        out_vnext[(long)n * DM + c] = vn;
        out_mu[(long)n * DM + c] = mu_s[c];
        out0[(long)n * DM + c] = h1;     // pre-MoE residual; down-GEMM adds y
    }
    float tot = blockReduceSum256(ssq);
    float rstd = rsqrtf(tot / (float)DM + 1e-6f);
    #pragma unroll
    for (int i = 0; i < 4; i++) {
        int c = tid + i * 256;
        x_bf[(long)n * DM + c] = f2b(h1v[i] * rstd * ln2_w[c]);
    }
}

// ---------------- MoE aux ----------------
__global__ void k_zero8(int* counts, int* fill) {
    if (threadIdx.x < NE) { counts[threadIdx.x] = 0; fill[threadIdx.x] = 0; }
}
__global__ void k_offsets(const int* counts, int* off) {
    if (threadIdx.x == 0) {
        int a = 0;
        for (int e = 0; e < NE; e++) { off[e] = a; a += counts[e]; }
        off[NE] = a;
    }
}
__global__ void k_scatter(const int* expert_id, const int* off, int* fill, int* perm) {
    int n = blockIdx.x * 256 + threadIdx.x;
    if (n < N_TOK) {
        int e = expert_id[n];
        int p = off[e] + atomicAdd(&fill[e], 1);
        perm[p] = n;
    }
}
__global__ __launch_bounds__(256) void k_gather(const int* __restrict__ perm,
                                                const bf16* __restrict__ x,
                                                bf16* __restrict__ xg) {
    int r = blockIdx.x;
    int tok = perm[r];
    ((int2*)(xg + (long)r * DM))[threadIdx.x] =
        ((const int2*)(x + (long)tok * DM))[threadIdx.x];
}
__global__ __launch_bounds__(256) void k_silumul(const bf16* __restrict__ gu,
                                                 bf16* __restrict__ mid) {
    long i = (long)blockIdx.x * 256 + threadIdx.x;   // over 2048*2048
    long r = i >> 11, c = i & 2047;
    float g = b2f(gu[r * 4096 + c]);
    float u = b2f(gu[r * 4096 + 2048 + c]);
    mid[i] = f2b(g / (1.f + __expf(-g)) * u);
}

// ---------------- launcher ----------------
extern "C" void kernel_launch(void* const* d_in, const int* in_sizes, int n_in,
                              void* d_out, int out_size, void* d_ws, size_t ws_size,
                              hipStream_t stream) {
    (void)in_sizes; (void)n_in; (void)out_size; (void)ws_size;
    const float* hidden     = (const float*)d_in[0];
    const int*   positions  = (const int*)d_in[1];
    const float* velocity   = (const float*)d_in[2];
    const int*   token_ids  = (const int*)d_in[3];
    const float* mu_prev    = (const float*)d_in[4];
    const float* ln1_w      = (const float*)d_in[5];
    const float* ln2_w      = (const float*)d_in[6];
    const float* wq         = (const float*)d_in[7];
    const float* wk         = (const float*)d_in[8];
    const float* wv         = (const float*)d_in[9];
    const float* wo         = (const float*)d_in[10];
    const float* w_mu_q     = (const float*)d_in[11];
    const float* w_mu_k     = (const float*)d_in[12];
    const float* w_mu_v     = (const float*)d_in[13];
    const float* qnorm_w    = (const float*)d_in[14];
    const float* knorm_w    = (const float*)d_in[15];
    const float* dyn_mu     = (const float*)d_in[16];
    const float* dyn_proj   = (const float*)d_in[17];
    const float* ctrl_in_w  = (const float*)d_in[18];
    const float* ctrl_in_b  = (const float*)d_in[19];
    const float* ctrl_out_w = (const float*)d_in[20];
    const float* ctrl_out_b = (const float*)d_in[21];
    const float* mu_router  = (const float*)d_in[22];
    const float* w_gate     = (const float*)d_in[23];
    const float* w_up       = (const float*)d_in[24];
    const float* w_down     = (const float*)d_in[25];

    float* out0 = (float*)d_out;
    float* out1 = out0 + (long)N_TOK * DM;
    float* out2 = out1 + (long)N_TOK * DM;

    char* p = (char*)d_ws;
    auto alloc = [&](size_t bytes) -> void* {
        void* r = (void*)p;
        p += (bytes + 255) & ~(size_t)255;
        return r;
    };
    // bf16 transposed weights
    bf16* WqkvT   = (bf16*)alloc((long)1536 * 2048 * 2);
    bf16* woT     = (bf16*)alloc((long)1024 * 1024 * 2);
    bf16* dynT    = (bf16*)alloc((long)1024 * 1024 * 2);
    bf16* ctrlinT = (bf16*)alloc((long)64 * 2048 * 2);
    bf16* ctrloutT= (bf16*)alloc((long)3072 * 64 * 2);
    bf16* gupT    = (bf16*)alloc((long)NE * 4096 * 1024 * 2);
    bf16* downT   = (bf16*)alloc((long)NE * 1024 * 2048 * 2);
    // activations
    bf16*  catA   = (bf16*)alloc((long)N_TOK * 2048 * 2);  // [h|mu_prev]; attn_bf alias
    bf16*  ctrlA  = (bf16*)alloc((long)N_TOK * 2048 * 2);  // [o_bf|vel_bf]
    float* qkv_f  = (float*)alloc((long)N_TOK * 1536 * 4); // x_bf/xg_bf/part alias
    bf16*  q_bf   = (bf16*)alloc((long)N_TOK * NH * DH * 2);
    bf16*  k_bf   = (bf16*)alloc((long)N_TOK * NKV * DH * 2);
    bf16*  v_bf   = (bf16*)alloc((long)N_TOK * NKV * DH * 2);
    bf16*  vt_bf  = (bf16*)alloc((long)NKV * DH * N_TOK * 2);
    float* o_f    = (float*)alloc((long)N_TOK * DM * 4);   // mid_bf alias
    float* mu_f   = (float*)alloc((long)N_TOK * DM * 4);
    float* coGu   = (float*)alloc((long)N_TOK * 3072 * 4); // opart+ml / co / gu_bf
    bf16*  ctrlbf = (bf16*)alloc((long)N_TOK * CH * 2);
    int*   expert_id = (int*)alloc(N_TOK * 4);
    int*   perm      = (int*)alloc(N_TOK * 4);
    int*   counts    = (int*)alloc(64 * 4);
    int*   fill      = (int*)alloc(64 * 4);
    int*   offs      = (int*)alloc(64 * 4);

    bf16*  attn_bf = catA;                                  // catA dead after QKV gemm
    bf16*  x_bf    = (bf16*)qkv_f;                          // qkv dead after qkv_post
    bf16*  xg_bf   = (bf16*)qkv_f + (long)N_TOK * DM;
    float* part    = (float*)((bf16*)qkv_f + (long)2 * N_TOK * DM);  // 8*2048*64 fp32
    float* opart   = coGu;                                  // 2*2048*1024 fp32 (16 MB)
    float2* ml     = (float2*)(coGu + (long)2 * N_TOK * DM);
    float* co_f    = coGu;                                  // opart dead after merge
    bf16*  gu_bf   = (bf16*)coGu;                           // co dead after k_ode
    bf16*  mid_bf  = (bf16*)o_f;                            // o_f dead after k_ode

    dim3 blk(256);
    k_zero8<<<1, 64, 0, stream>>>(counts, fill);

    // ---- weight transposes (fp32 KxN -> bf16 NxK) ----
    k_transpose<<<dim3(16,16,1), blk, 0, stream>>>(wq, 0, 1024, WqkvT, 0, 2048);
    k_transpose<<<dim3(4,16,1),  blk, 0, stream>>>(wk, 0, 256,  WqkvT + (long)1024*2048, 0, 2048);
    k_transpose<<<dim3(4,16,1),  blk, 0, stream>>>(wv, 0, 256,  WqkvT + (long)1280*2048, 0, 2048);
    k_transpose<<<dim3(16,16,1), blk, 0, stream>>>(w_mu_q, 0, 1024, WqkvT + 1024, 0, 2048);
    k_transpose<<<dim3(4,16,1),  blk, 0, stream>>>(w_mu_k, 0, 256,  WqkvT + (long)1024*2048 + 1024, 0, 2048);
    k_transpose<<<dim3(4,16,1),  blk, 0, stream>>>(w_mu_v, 0, 256,  WqkvT + (long)1280*2048 + 1024, 0, 2048);
    k_transpose<<<dim3(16,16,1), blk, 0, stream>>>(wo, 0, 1024, woT, 0, 1024);
    k_transpose<<<dim3(16,16,1), blk, 0, stream>>>(dyn_proj, 0, 1024, dynT, 0, 1024);
    k_transpose<<<dim3(1,32,1),  blk, 0, stream>>>(ctrl_in_w, 0, 64, ctrlinT, 0, 2048);
    k_transpose<<<dim3(48,1,1),  blk, 0, stream>>>(ctrl_out_w, 0, 3072, ctrloutT, 0, 64);
    k_transpose<<<dim3(32,16,NE), blk, 0, stream>>>(w_gate, (long)1024*2048, 2048,
        gupT, (long)4096*1024, 1024);
    k_transpose<<<dim3(32,16,NE), blk, 0, stream>>>(w_up, (long)1024*2048, 2048,
        gupT + (long)2048*1024, (long)4096*1024, 1024);
    k_transpose<<<dim3(16,32,NE), blk, 0, stream>>>(w_down, (long)2048*1024, 1024,
        downT, (long)1024*2048, 2048);

    // ---- activation prep (rmsnorm + 2 casts fused) ----
    k_prep<<<N_TOK, blk, 0, stream>>>(hidden, ln1_w, mu_prev, velocity, catA, ctrlA);

    // ---- QKV: qkv = [h|mu] @ [Wqkv; Wmu]  (M=2048,N=1536,K=2048) ----
    k_gemm<<<dim3(12,16,1), blk, 0, stream>>>(catA, 2048, WqkvT, 2048, 0,
        qkv_f, 1536, nullptr, nullptr, 0, 2048, GEMM_WRITE, nullptr, nullptr, nullptr);

    k_qkv_post<<<N_TOK, blk, 0, stream>>>(qkv_f, positions, qnorm_w, knorm_w, q_bf, k_bf, v_bf);
    k_vt<<<dim3(32,1,NKV), blk, 0, stream>>>(v_bf, vt_bf);
    k_attn<<<dim3(32,16,2), blk, 0, stream>>>(q_bf, k_bf, vt_bf, opart, ml);
    k_attn_merge<<<N_TOK, blk, 0, stream>>>(opart, ml, attn_bf);

    // ---- o = attn @ wo  (fp32 o_f + bf16 into ctrlA[:,0:1024]) ----
    k_gemm<<<dim3(8,16,1), blk, 0, stream>>>(attn_bf, 1024, woT, 1024, 0,
        o_f, 1024, nullptr, ctrlA, 2048, 1024, GEMM_WRITE | GEMM_WRITEB,
        nullptr, nullptr, nullptr);
    // ---- mu = dyn_mu + o @ dyn_proj ----
    k_gemm<<<dim3(8,16,1), blk, 0, stream>>>(ctrlA, 2048, dynT, 1024, 0,
        mu_f, 1024, dyn_mu, nullptr, 0, 1024, GEMM_WRITE | GEMM_BIAS,
        nullptr, nullptr, nullptr);

    // ---- ctrl chain ----
    k_ctrl_gemm<<<dim3(16,8,1), blk, 0, stream>>>(ctrlA, ctrlinT, part);
    k_silu_ctrl<<<(N_TOK * CH) / 256, blk, 0, stream>>>(part, ctrl_in_b, ctrlbf);
    k_gemm<<<dim3(24,16,1), blk, 0, stream>>>(ctrlbf, 64, ctrloutT, 64, 0,
        co_f, 3072, ctrl_out_b, nullptr, 0, 64, GEMM_WRITE | GEMM_BIAS,
        nullptr, nullptr, nullptr);

    k_ode<<<N_TOK, blk, 0, stream>>>(co_f, o_f, velocity, mu_f, hidden,
        mu_router, token_ids, ln2_w, out0, out1, out2, x_bf, expert_id, counts);

    k_offsets<<<1, 64, 0, stream>>>(counts, offs);
    k_scatter<<<NE, blk, 0, stream>>>(expert_id, offs, fill, perm);
    k_gather<<<N_TOK, blk, 0, stream>>>(perm, x_bf, xg_bf);

    // ---- MoE: [gate|up] combined (N=4096), then silu*mul, then down ----
    k_gemm<<<dim3(32,16,NE), blk, 0, stream>>>(xg_bf, 1024, gupT, 1024, (long)4096*1024,
        nullptr, 0, nullptr, gu_bf, 4096, 1024, GEMM_WRITEB, offs, nullptr, nullptr);
    k_silumul<<<(N_TOK * FF) / 256, blk, 0, stream>>>(gu_bf, mid_bf);
    k_gemm<<<dim3(8,16,NE), blk, 0, stream>>>(mid_bf, 2048, downT, 2048, (long)1024*2048,
        nullptr, 1024, nullptr, nullptr, 0, 2048, GEMM_DOWN, offs, perm, out0);
}

// Round 7
// 642.249 us; speedup vs baseline: 3.3566x; 1.1483x over previous
//
#include <hip/hip_runtime.h>
#include <hip/hip_bf16.h>
#include <math.h>

typedef __hip_bfloat16 bf16;
typedef __attribute__((ext_vector_type(8))) short short8;
typedef __attribute__((ext_vector_type(4))) float floatx4;

#define N_TOK 2048
#define DM    1024
#define NH    16
#define NKV   4
#define DH    64
#define NE    8
#define FF    2048
#define CH    64

__device__ __forceinline__ float b2f(bf16 x) { return __bfloat162float(x); }
__device__ __forceinline__ bf16  f2b(float x) { return __float2bfloat16(x); }
__device__ __forceinline__ short f2s(float x) { bf16 t = __float2bfloat16(x); return *(short*)&t; }

// async global->LDS, 16B per lane; LDS dest = wave-uniform base + lane*16
#define GLL16(g, l) __builtin_amdgcn_global_load_lds( \
    (const __attribute__((address_space(1))) void*)(g), \
    (__attribute__((address_space(3))) void*)(l), 16, 0, 0)

__device__ __forceinline__ float blockReduceSum256(float v) {
    __shared__ float tmp[4];
    #pragma unroll
    for (int m = 1; m < 64; m <<= 1) v += __shfl_xor(v, m, 64);
    if ((threadIdx.x & 63) == 0) tmp[threadIdx.x >> 6] = v;
    __syncthreads();
    float r = tmp[0] + tmp[1] + tmp[2] + tmp[3];
    __syncthreads();
    return r;
}

// ---------------- transpose fp32 KxN -> bf16 NxK ----------------
__global__ __launch_bounds__(256) void k_transpose(
    const float* __restrict__ src, long sstrideE, int sN,
    bf16* __restrict__ dst, long dstrideE, int ldk)
{
    __shared__ float tile[64][65];
    const float* s = src + (long)blockIdx.z * sstrideE;
    bf16* d = dst + (long)blockIdx.z * dstrideE;
    int n0 = blockIdx.x * 64, k0 = blockIdx.y * 64;
    int tid = threadIdx.x;
    int c = tid & 63, r4 = tid >> 6;
    #pragma unroll
    for (int i = 0; i < 16; i++) {
        int r = i * 4 + r4;
        tile[r][c] = s[(long)(k0 + r) * sN + n0 + c];
    }
    __syncthreads();
    int c2 = (tid & 31) * 2, rr = tid >> 5;
    #pragma unroll
    for (int i = 0; i < 8; i++) {
        int r = i * 8 + rr;
        short2 o;
        o.x = f2s(tile[c2][r]);
        o.y = f2s(tile[c2 + 1][r]);
        *(short2*)(d + (long)(n0 + r) * ldk + k0 + c2) = o;
    }
}

// ---------------- fused: rmsnorm(hidden)->catA[:,0:1024], cvt mu/vel -------
__global__ __launch_bounds__(256) void k_prep(
    const float* __restrict__ hidden, const float* __restrict__ ln1_w,
    const float* __restrict__ mu_prev, const float* __restrict__ velocity,
    bf16* __restrict__ catA, bf16* __restrict__ ctrlA)
{
    int n = blockIdx.x, tid = threadIdx.x;
    float ss = 0.f, vals[4];
    #pragma unroll
    for (int i = 0; i < 4; i++) {
        int c = tid + i * 256;
        vals[i] = hidden[(long)n * DM + c];
        ss += vals[i] * vals[i];
        catA[(long)n * 2048 + 1024 + c] = f2b(mu_prev[(long)n * DM + c]);
        ctrlA[(long)n * 2048 + 1024 + c] = f2b(velocity[(long)n * DM + c]);
    }
    float tot = blockReduceSum256(ss);
    float r = rsqrtf(tot / (float)DM + 1e-6f);
    #pragma unroll
    for (int i = 0; i < 4; i++) {
        int c = tid + i * 256;
        catA[(long)n * 2048 + c] = f2b(vals[i] * r * ln1_w[c]);
    }
}

// ---------------- generic 128x128 MFMA GEMM, bf16 A (MxK) x bf16 B^T (NxK) -
// nsplit>1: K split over blockIdx.z%nsplit, raw fp32 partials to
//           C[kc*strideKc + row*ldc + col]; flags ignored.
#define GEMM_WRITE  1
#define GEMM_BIAS   2
#define GEMM_WRITEB 4
#define GEMM_DOWN   8

__global__ __launch_bounds__(256) void k_gemm(
    const bf16* __restrict__ A, int lda,
    const bf16* __restrict__ Bt, int ldb, long strideBe,
    float* __restrict__ C, int ldc,
    const float* __restrict__ bias,
    bf16* __restrict__ Cb, int ldcb,
    int K, int flags,
    int nsplit, long strideKc,
    const int* __restrict__ grp_off,
    const int* __restrict__ perm,
    float* __restrict__ outp)
{
    __shared__ __align__(16) short As[128 * 32];
    __shared__ __align__(16) short Bs[128 * 32];
    int tid = threadIdx.x;
    int e = blockIdx.z, kc = 0;
    if (nsplit > 1) { e = blockIdx.z / nsplit; kc = blockIdx.z % nsplit; }
    int rowBase, rowsValid;
    const bf16* Bp = Bt;
    if (grp_off) {
        int r0 = grp_off[e], r1 = grp_off[e + 1];
        int rt = blockIdx.y * 128;
        rowsValid = (r1 - r0) - rt;
        if (rowsValid <= 0) return;
        if (rowsValid > 128) rowsValid = 128;
        rowBase = r0 + rt;
        Bp = Bt + (long)e * strideBe;
    } else {
        rowBase = blockIdx.y * 128;
        rowsValid = 128;
    }
    int n0 = blockIdx.x * 128;
    int Kc = K / nsplit;
    int kbeg = kc * Kc, kend = kbeg + Kc;

    floatx4 acc[4][4];
    #pragma unroll
    for (int i = 0; i < 4; i++)
        #pragma unroll
        for (int j = 0; j < 4; j++) acc[i][j] = (floatx4){0.f, 0.f, 0.f, 0.f};

    int wave = tid >> 6, lane = tid & 63;
    int wm = (wave >> 1) * 64, wn = (wave & 1) * 64;
    int lrow = lane & 15, quad = lane >> 4;

    int c0 = wave * 2;
    int srow0 = c0 * 16 + (lane >> 2);
    int srow1 = (c0 + 1) * 16 + (lane >> 2);
    int skoff = (lane & 3) * 8;
    short* ldsA0 = As + c0 * 512;
    short* ldsA1 = As + (c0 + 1) * 512;
    short* ldsB0 = Bs + c0 * 512;
    short* ldsB1 = Bs + (c0 + 1) * 512;

    for (int k0 = kbeg; k0 < kend; k0 += 32) {
        if (srow0 < rowsValid) GLL16(A + (long)(rowBase + srow0) * lda + k0 + skoff, ldsA0);
        if (srow1 < rowsValid) GLL16(A + (long)(rowBase + srow1) * lda + k0 + skoff, ldsA1);
        GLL16(Bp + (long)(n0 + srow0) * ldb + k0 + skoff, ldsB0);
        GLL16(Bp + (long)(n0 + srow1) * ldb + k0 + skoff, ldsB1);
        __syncthreads();
        short8 af[4], bfr[4];
        #pragma unroll
        for (int mi = 0; mi < 4; mi++)
            af[mi] = *(const short8*)(&As[(wm + mi * 16 + lrow) * 32 + quad * 8]);
        #pragma unroll
        for (int ni = 0; ni < 4; ni++)
            bfr[ni] = *(const short8*)(&Bs[(wn + ni * 16 + lrow) * 32 + quad * 8]);
        #pragma unroll
        for (int mi = 0; mi < 4; mi++)
            #pragma unroll
            for (int ni = 0; ni < 4; ni++)
                acc[mi][ni] = __builtin_amdgcn_mfma_f32_16x16x32_bf16(
                    af[mi], bfr[ni], acc[mi][ni], 0, 0, 0);
        __syncthreads();
    }

    #pragma unroll
    for (int mi = 0; mi < 4; mi++) {
        #pragma unroll
        for (int ni = 0; ni < 4; ni++) {
            #pragma unroll
            for (int r = 0; r < 4; r++) {
                int rl = wm + mi * 16 + quad * 4 + r;
                if (rl >= rowsValid) continue;
                int grow = rowBase + rl;
                int gcol = n0 + wn + ni * 16 + lrow;
                float v = acc[mi][ni][r];
                if (nsplit > 1) {
                    C[kc * strideKc + (long)grow * ldc + gcol] = v;
                    continue;
                }
                if (flags & GEMM_BIAS) v += bias[gcol];
                if (flags & GEMM_DOWN) {
                    int tok = perm[grow];
                    float* o = &outp[(long)tok * ldc + gcol];
                    *o = *o + v;
                } else {
                    if (flags & GEMM_WRITE) C[(long)grow * ldc + gcol] = v;
                    if (flags & GEMM_WRITEB) Cb[(long)grow * ldcb + gcol] = f2b(v);
                }
            }
        }
    }
}

// ---------------- split-K reduce: wo (o_f fp32 + ctrlA bf16) ---------------
__global__ __launch_bounds__(256) void k_red_wo(const float* __restrict__ p,
                                                float* __restrict__ o_f,
                                                bf16* __restrict__ ctrlA) {
    int n = blockIdx.x, tid = threadIdx.x;
    #pragma unroll
    for (int i = 0; i < 4; i++) {
        int c = tid + i * 256;
        float v = p[(long)n * DM + c] + p[(long)N_TOK * DM + (long)n * DM + c];
        o_f[(long)n * DM + c] = v;
        ctrlA[(long)n * 2048 + c] = f2b(v);
    }
}

// ---------------- split-K reduce: down (4 partials, perm scatter, +=) ------
__global__ __launch_bounds__(256) void k_red_down(const float* __restrict__ p,
                                                  const int* __restrict__ perm,
                                                  float* __restrict__ out0) {
    int r = blockIdx.x, tid = threadIdx.x;
    int tok = perm[r];
    #pragma unroll
    for (int i = 0; i < 4; i++) {
        int c = tid + i * 256;
        long idx = (long)r * DM + c;
        float v = p[idx] + p[(long)N_TOK * DM + idx] +
                  p[(long)2 * N_TOK * DM + idx] + p[(long)3 * N_TOK * DM + idx];
        out0[(long)tok * DM + c] += v;
    }
}

// ---------------- ctrl_in GEMM: part[kc] = [o|vel] @ W_in (K-chunked) ------
__global__ __launch_bounds__(256) void k_ctrl_gemm(
    const bf16* __restrict__ A,      // ctrlA 2048 x 2048
    const bf16* __restrict__ Bt,     // ctrl_inT 64 x 2048
    float* __restrict__ part)        // [8][2048][64]
{
    __shared__ __align__(16) short As[128 * 32];
    __shared__ __align__(16) short Bs[64 * 32];
    int tid = threadIdx.x;
    int rowBase = blockIdx.x * 128;
    int kbeg = blockIdx.y * 256;
    int wave = tid >> 6, lane = tid & 63;
    int wm = wave * 32, lrow = lane & 15, quad = lane >> 4;
    int srow = lane >> 2, skoff = (lane & 3) * 8;

    floatx4 acc[2][4];
    #pragma unroll
    for (int i = 0; i < 2; i++)
        #pragma unroll
        for (int j = 0; j < 4; j++) acc[i][j] = (floatx4){0.f, 0.f, 0.f, 0.f};

    short* ldsA0 = As + (wave * 2) * 512;
    short* ldsA1 = As + (wave * 2 + 1) * 512;
    short* ldsB  = Bs + wave * 512;

    for (int k0 = kbeg; k0 < kbeg + 256; k0 += 32) {
        GLL16(A + (long)(rowBase + wave * 32 + srow) * 2048 + k0 + skoff, ldsA0);
        GLL16(A + (long)(rowBase + wave * 32 + 16 + srow) * 2048 + k0 + skoff, ldsA1);
        GLL16(Bt + (long)(wave * 16 + srow) * 2048 + k0 + skoff, ldsB);
        __syncthreads();
        short8 af[2], bfr[4];
        af[0] = *(const short8*)(&As[(wm + lrow) * 32 + quad * 8]);
        af[1] = *(const short8*)(&As[(wm + 16 + lrow) * 32 + quad * 8]);
        #pragma unroll
        for (int ni = 0; ni < 4; ni++)
            bfr[ni] = *(const short8*)(&Bs[(ni * 16 + lrow) * 32 + quad * 8]);
        #pragma unroll
        for (int mi = 0; mi < 2; mi++)
            #pragma unroll
            for (int ni = 0; ni < 4; ni++)
                acc[mi][ni] = __builtin_amdgcn_mfma_f32_16x16x32_bf16(
                    af[mi], bfr[ni], acc[mi][ni], 0, 0, 0);
        __syncthreads();
    }
    #pragma unroll
    for (int mi = 0; mi < 2; mi++)
        #pragma unroll
        for (int ni = 0; ni < 4; ni++)
            #pragma unroll
            for (int r = 0; r < 4; r++) {
                int grow = rowBase + wm + mi * 16 + quad * 4 + r;
                part[((long)blockIdx.y * N_TOK + grow) * 64 + ni * 16 + lrow] = acc[mi][ni][r];
            }
}

__global__ __launch_bounds__(256) void k_silu_ctrl(const float* __restrict__ part,
                                                   const float* __restrict__ b,
                                                   bf16* __restrict__ out) {
    int i = blockIdx.x * 256 + threadIdx.x;     // 2048*64
    float a = b[i & 63];
    #pragma unroll
    for (int kc = 0; kc < 8; kc++) a += part[(long)kc * (N_TOK * 64) + i];
    out[i] = f2b(a / (1.f + __expf(-a)));
}

// ---------------- qk norm + rope + split (sums 2 K-split partials) ---------
__global__ __launch_bounds__(256) void k_qkv_post(
    const float* __restrict__ qkvp, const int* __restrict__ positions,
    const float* __restrict__ qnw, const float* __restrict__ knw,
    bf16* __restrict__ q, bf16* __restrict__ k, bf16* __restrict__ v)
{
    int n = blockIdx.x;
    int wave = threadIdx.x >> 6, lane = threadIdx.x & 63;
    float pos = (float)positions[n];
    int i = lane & 31;
    float invf = exp2f(-(float)(2 * i) * (13.287712379549449f / 64.f));
    float ang = pos * invf;
    float c = cosf(ang), s = sinf(ang);

    #pragma unroll
    for (int si = 0; si < 6; si++) {
        int slot = wave + si * 4;  // 0..23
        long base = (long)n * 1536 +
                    (slot < 16 ? slot * 64
                               : (slot < 20 ? 1024 + (slot - 16) * 64
                                            : 1280 + (slot - 20) * 64));
        float val = qkvp[base + lane] + qkvp[(long)N_TOK * 1536 + base + lane];
        if (slot < 20) {
            float ss = val * val;
            #pragma unroll
            for (int m = 1; m < 64; m <<= 1) ss += __shfl_xor(ss, m, 64);
            float r = rsqrtf(ss / 64.f + 1e-6f);
            float wn = (slot < 16 ? qnw[lane] : knw[lane]);
            float xn = val * r * wn;
            float partner = __shfl_xor(xn, 32, 64);
            float out = (lane < 32) ? (xn * c - partner * s) : (xn * c + partner * s);
            if (slot < 16) q[((long)n * NH + slot) * 64 + lane] = f2b(out);
            else           k[((long)n * NKV + (slot - 16)) * 64 + lane] = f2b(out);
        } else {
            v[((long)n * NKV + (slot - 20)) * 64 + lane] = f2b(val);
        }
    }
}

// ---------------- V transpose: v[n][kv][d] -> vt[kv*64+d][n] ---------------
__global__ __launch_bounds__(256) void k_vt(const bf16* __restrict__ v,
                                            bf16* __restrict__ vt) {
    __shared__ short tile[64][65];
    int kv = blockIdx.z, n0 = blockIdx.x * 64;
    int tid = threadIdx.x;
    int c = tid & 63, r4 = tid >> 6;
    const short* vs = (const short*)v;
    #pragma unroll
    for (int i = 0; i < 16; i++) {
        int r = i * 4 + r4;
        tile[r][c] = vs[(long)(n0 + r) * 256 + kv * 64 + c];
    }
    __syncthreads();
    #pragma unroll
    for (int i = 0; i < 16; i++) {
        int d = i * 4 + r4;
        ((short*)vt)[(long)(kv * 64 + d) * 2048 + n0 + c] = tile[c][d];
    }
}

// ---------------- flash attention, KV-split (partials) ----------------
__global__ __launch_bounds__(256) void k_attn(
    const bf16* __restrict__ q, const bf16* __restrict__ k,
    const bf16* __restrict__ vt,
    float* __restrict__ opart, float2* __restrict__ ml)
{
    const int h = blockIdx.y;
    const int qbase = blockIdx.x * 64;
    const int z = blockIdx.z;
    const int kvh = h >> 2;
    __shared__ __align__(16) short Qs[64 * 72];
    __shared__ __align__(16) short Ks[64 * 72];
    __shared__ __align__(16) short Vt[64 * 72];
    __shared__ __align__(16) short Ps[4 * 16 * 72];
    int tid = threadIdx.x, wave = tid >> 6, lane = tid & 63;
    int lrow = lane & 15, quad = lane >> 4;

    #pragma unroll
    for (int i = 0; i < 2; i++) {
        int lin = tid + i * 256;
        int r = lin >> 3, dc = (lin & 7) << 3;
        short8 vq = *(const short8*)(q + ((long)(qbase + r) * NH + h) * 64 + dc);
        *(short8*)&Qs[r * 72 + dc] = vq;
    }
    float m_i[4], l_i[4];
    floatx4 oacc[4];
    #pragma unroll
    for (int r = 0; r < 4; r++) { m_i[r] = -1e30f; l_i[r] = 0.f; }
    #pragma unroll
    for (int di = 0; di < 4; di++) oacc[di] = (floatx4){0.f, 0.f, 0.f, 0.f};
    const float scale = 0.125f;
    __syncthreads();

    const int kt0 = z * (N_TOK / 2);
    for (int kt = kt0; kt < kt0 + N_TOK / 2; kt += 64) {
        #pragma unroll
        for (int i = 0; i < 2; i++) {
            int lin = tid + i * 256;
            int r = lin >> 3, dc = (lin & 7) << 3;
            short8 k8 = *(const short8*)(k + ((long)(kt + r) * NKV + kvh) * 64 + dc);
            *(short8*)&Ks[r * 72 + dc] = k8;
            short8 v8 = *(const short8*)(vt + (long)(kvh * 64 + r) * 2048 + kt + dc);
            *(short8*)&Vt[r * 72 + dc] = v8;
        }
        __syncthreads();

        short8 aq0 = *(const short8*)&Qs[(wave * 16 + lrow) * 72 + quad * 8];
        short8 aq1 = *(const short8*)&Qs[(wave * 16 + lrow) * 72 + 32 + quad * 8];
        floatx4 sv[4];
        #pragma unroll
        for (int kn = 0; kn < 4; kn++) {
            short8 b0 = *(const short8*)&Ks[(kn * 16 + lrow) * 72 + quad * 8];
            short8 b1 = *(const short8*)&Ks[(kn * 16 + lrow) * 72 + 32 + quad * 8];
            floatx4 t = (floatx4){0.f, 0.f, 0.f, 0.f};
            t = __builtin_amdgcn_mfma_f32_16x16x32_bf16(aq0, b0, t, 0, 0, 0);
            t = __builtin_amdgcn_mfma_f32_16x16x32_bf16(aq1, b1, t, 0, 0, 0);
            sv[kn] = t;
        }
        #pragma unroll
        for (int kn = 0; kn < 4; kn++)
            #pragma unroll
            for (int r = 0; r < 4; r++) sv[kn][r] *= scale;

        #pragma unroll
        for (int r = 0; r < 4; r++) {
            float mx = fmaxf(fmaxf(sv[0][r], sv[1][r]), fmaxf(sv[2][r], sv[3][r]));
            #pragma unroll
            for (int msk = 1; msk < 16; msk <<= 1) mx = fmaxf(mx, __shfl_xor(mx, msk, 64));
            float mnew = fmaxf(m_i[r], mx);
            float alpha = __expf(m_i[r] - mnew);
            m_i[r] = mnew;
            l_i[r] *= alpha;
            #pragma unroll
            for (int di = 0; di < 4; di++) oacc[di][r] *= alpha;
            float rowsum = 0.f;
            #pragma unroll
            for (int kn = 0; kn < 4; kn++) {
                float pp = __expf(sv[kn][r] - mnew);
                sv[kn][r] = pp;
                rowsum += pp;
            }
            #pragma unroll
            for (int msk = 1; msk < 16; msk <<= 1) rowsum += __shfl_xor(rowsum, msk, 64);
            l_i[r] += rowsum;
        }
        #pragma unroll
        for (int kn = 0; kn < 4; kn++)
            #pragma unroll
            for (int r = 0; r < 4; r++)
                Ps[(wave * 16 + quad * 4 + r) * 72 + kn * 16 + lrow] = f2s(sv[kn][r]);
        __syncthreads();

        short8 ap0 = *(const short8*)&Ps[(wave * 16 + lrow) * 72 + quad * 8];
        short8 ap1 = *(const short8*)&Ps[(wave * 16 + lrow) * 72 + 32 + quad * 8];
        #pragma unroll
        for (int di = 0; di < 4; di++) {
            short8 bv0 = *(const short8*)&Vt[(di * 16 + lrow) * 72 + quad * 8];
            short8 bv1 = *(const short8*)&Vt[(di * 16 + lrow) * 72 + 32 + quad * 8];
            oacc[di] = __builtin_amdgcn_mfma_f32_16x16x32_bf16(ap0, bv0, oacc[di], 0, 0, 0);
            oacc[di] = __builtin_amdgcn_mfma_f32_16x16x32_bf16(ap1, bv1, oacc[di], 0, 0, 0);
        }
        __syncthreads();
    }

    #pragma unroll
    for (int di = 0; di < 4; di++)
        #pragma unroll
        for (int r = 0; r < 4; r++) {
            int n = qbase + wave * 16 + quad * 4 + r;
            opart[((long)z * N_TOK + n) * DM + h * 64 + di * 16 + lrow] = oacc[di][r];
        }
    if (lrow == 0) {
        #pragma unroll
        for (int r = 0; r < 4; r++) {
            int n = qbase + wave * 16 + quad * 4 + r;
            ml[(long)(z * NH + h) * N_TOK + n] = make_float2(m_i[r], l_i[r]);
        }
    }
}

// ---------------- merge KV-split partials -> attn_out bf16 ----------------
__global__ __launch_bounds__(256) void k_attn_merge(
    const float* __restrict__ opart, const float2* __restrict__ ml,
    bf16* __restrict__ attn_out)
{
    int n = blockIdx.x, tid = threadIdx.x;
    __shared__ float2 sml[2][NH];
    if (tid < 32) {
        int z = tid >> 4, hh = tid & 15;
        sml[z][hh] = ml[(long)(z * NH + hh) * N_TOK + n];
    }
    __syncthreads();
    #pragma unroll
    for (int i = 0; i < 4; i++) {
        int c = tid + i * 256;
        int h = c >> 6;
        float2 a = sml[0][h], b = sml[1][h];
        float M = fmaxf(a.x, b.x);
        float w0 = __expf(a.x - M), w1 = __expf(b.x - M);
        float num = w0 * opart[(long)n * DM + c] +
                    w1 * opart[((long)N_TOK + n) * DM + c];
        float den = w0 * a.y + w1 * b.y;
        attn_out[(long)n * DM + c] = f2b(num / den);
    }
}

// ---------------- ODE + router + rmsnorm2 (sums dyn split partials) --------
__global__ __launch_bounds__(256) void k_ode(
    const float* __restrict__ co, const float* __restrict__ o_f,
    const float* __restrict__ velocity, const float* __restrict__ mup,
    const float* __restrict__ dyn_mu, const float* __restrict__ hidden_in,
    const float* __restrict__ mu_router_w, const int* __restrict__ token_ids,
    const float* __restrict__ ln2_w,
    float* __restrict__ out0, float* __restrict__ out_vnext,
    float* __restrict__ out_mu, bf16* __restrict__ x_bf,
    int* __restrict__ expert_id, int* __restrict__ counts)
{
    int n = blockIdx.x, tid = threadIdx.x;
    __shared__ float mu_s[DM];
    __shared__ float red2[32][8];

    #pragma unroll
    for (int i = 0; i < 4; i++) {
        int c = tid + i * 256;
        mu_s[c] = mup[(long)n * DM + c] + mup[(long)N_TOK * DM + (long)n * DM + c]
                + dyn_mu[c];
    }
    __syncthreads();

    {
        int e = tid & 7, kc = tid >> 3;
        float a = 0.f;
        #pragma unroll
        for (int kk = 0; kk < 32; kk++) {
            int k = kc * 32 + kk;
            a += mu_s[k] * mu_router_w[k * NE + e];
        }
        red2[kc][e] = a;
    }
    __syncthreads();
    if (tid == 0) {
        int bid = token_ids[n] & (NE - 1);
        float best = -1e30f; int bi = 0;
        for (int e = 0; e < NE; e++) {
            float lg = (e == bid ? 10.f : 0.f);
            for (int j = 0; j < 32; j++) lg += red2[j][e];
            if (lg > best) { best = lg; bi = e; }
        }
        expert_id[n] = bi;
        atomicAdd(&counts[bi], 1);
    }

    float ssq = 0.f;
    float h1v[4];
    #pragma unroll
    for (int i = 0; i < 4; i++) {
        int c = tid + i * 256;
        float coa = co[(long)n * 3072 + c];
        float cob = co[(long)n * 3072 + DM + c];
        float cog = co[(long)n * 3072 + 2 * DM + c];
        float alpha = 1.f / (1.f + __expf(-coa));
        float sp = (cob > 20.f) ? cob : log1pf(__expf(cob));
        float beta = fminf(sp, 2.0f);
        float gate = 1.f / (1.f + __expf(-cog));
        float ov = o_f[(long)n * DM + c];
        float vv = velocity[(long)n * DM + c];
        float err = ov - mu_s[c];
        float vn = fminf(fmaxf(alpha * vv - beta * err, -10.f), 10.f);
        float hn = ov + 0.1f * gate * vn;
        float h1 = hidden_in[(long)n * DM + c] + hn;
        h1v[i] = h1;
        ssq += h1 * h1;
        out_vnext[(long)n * DM + c] = vn;
        out_mu[(long)n * DM + c] = mu_s[c];
        out0[(long)n * DM + c] = h1;     // pre-MoE residual; k_red_down adds y
    }
    float tot = blockReduceSum256(ssq);
    float rstd = rsqrtf(tot / (float)DM + 1e-6f);
    #pragma unroll
    for (int i = 0; i < 4; i++) {
        int c = tid + i * 256;
        x_bf[(long)n * DM + c] = f2b(h1v[i] * rstd * ln2_w[c]);
    }
}

// ---------------- MoE aux ----------------
__global__ void k_zero8(int* counts, int* fill) {
    if (threadIdx.x < NE) { counts[threadIdx.x] = 0; fill[threadIdx.x] = 0; }
}
__global__ void k_offsets(const int* counts, int* off) {
    if (threadIdx.x == 0) {
        int a = 0;
        for (int e = 0; e < NE; e++) { off[e] = a; a += counts[e]; }
        off[NE] = a;
    }
}
__global__ void k_scatter(const int* expert_id, const int* off, int* fill, int* perm) {
    int n = blockIdx.x * 256 + threadIdx.x;
    if (n < N_TOK) {
        int e = expert_id[n];
        int p = off[e] + atomicAdd(&fill[e], 1);
        perm[p] = n;
    }
}
__global__ __launch_bounds__(256) void k_gather(const int* __restrict__ perm,
                                                const bf16* __restrict__ x,
                                                bf16* __restrict__ xg) {
    int r = blockIdx.x;
    int tok = perm[r];
    ((int2*)(xg + (long)r * DM))[threadIdx.x] =
        ((const int2*)(x + (long)tok * DM))[threadIdx.x];
}
__global__ __launch_bounds__(256) void k_silumul(const bf16* __restrict__ gu,
                                                 bf16* __restrict__ mid) {
    long i = (long)blockIdx.x * 256 + threadIdx.x;   // over 2048*2048
    long r = i >> 11, c = i & 2047;
    float g = b2f(gu[r * 4096 + c]);
    float u = b2f(gu[r * 4096 + 2048 + c]);
    mid[i] = f2b(g / (1.f + __expf(-g)) * u);
}

// ---------------- launcher ----------------
extern "C" void kernel_launch(void* const* d_in, const int* in_sizes, int n_in,
                              void* d_out, int out_size, void* d_ws, size_t ws_size,
                              hipStream_t stream) {
    (void)in_sizes; (void)n_in; (void)out_size; (void)ws_size;
    const float* hidden     = (const float*)d_in[0];
    const int*   positions  = (const int*)d_in[1];
    const float* velocity   = (const float*)d_in[2];
    const int*   token_ids  = (const int*)d_in[3];
    const float* mu_prev    = (const float*)d_in[4];
    const float* ln1_w      = (const float*)d_in[5];
    const float* ln2_w      = (const float*)d_in[6];
    const float* wq         = (const float*)d_in[7];
    const float* wk         = (const float*)d_in[8];
    const float* wv         = (const float*)d_in[9];
    const float* wo         = (const float*)d_in[10];
    const float* w_mu_q     = (const float*)d_in[11];
    const float* w_mu_k     = (const float*)d_in[12];
    const float* w_mu_v     = (const float*)d_in[13];
    const float* qnorm_w    = (const float*)d_in[14];
    const float* knorm_w    = (const float*)d_in[15];
    const float* dyn_mu     = (const float*)d_in[16];
    const float* dyn_proj   = (const float*)d_in[17];
    const float* ctrl_in_w  = (const float*)d_in[18];
    const float* ctrl_in_b  = (const float*)d_in[19];
    const float* ctrl_out_w = (const float*)d_in[20];
    const float* ctrl_out_b = (const float*)d_in[21];
    const float* mu_router  = (const float*)d_in[22];
    const float* w_gate     = (const float*)d_in[23];
    const float* w_up       = (const float*)d_in[24];
    const float* w_down     = (const float*)d_in[25];

    float* out0 = (float*)d_out;
    float* out1 = out0 + (long)N_TOK * DM;
    float* out2 = out1 + (long)N_TOK * DM;

    char* p = (char*)d_ws;
    auto alloc = [&](size_t bytes) -> void* {
        void* r = (void*)p;
        p += (bytes + 255) & ~(size_t)255;
        return r;
    };
    // bf16 transposed weights
    bf16* WqkvT   = (bf16*)alloc((long)1536 * 2048 * 2);
    bf16* woT     = (bf16*)alloc((long)1024 * 1024 * 2);
    bf16* dynT    = (bf16*)alloc((long)1024 * 1024 * 2);
    bf16* ctrlinT = (bf16*)alloc((long)64 * 2048 * 2);
    bf16* ctrloutT= (bf16*)alloc((long)3072 * 64 * 2);
    bf16* gupT    = (bf16*)alloc((long)NE * 4096 * 1024 * 2);
    bf16* downT   = (bf16*)alloc((long)NE * 1024 * 2048 * 2);
    // activations
    bf16*  catA   = (bf16*)alloc((long)N_TOK * 2048 * 2);  // [h|mu_prev]; attn_bf alias
    bf16*  ctrlA  = (bf16*)alloc((long)N_TOK * 2048 * 2);  // [o_bf|vel_bf]
    float* xbuf   = (float*)alloc((long)N_TOK * 1536 * 4); // x_bf/xg_bf/ctrl-part
    bf16*  q_bf   = (bf16*)alloc((long)N_TOK * NH * DH * 2);
    bf16*  k_bf   = (bf16*)alloc((long)N_TOK * NKV * DH * 2);
    bf16*  v_bf   = (bf16*)alloc((long)N_TOK * NKV * DH * 2);
    bf16*  vt_bf  = (bf16*)alloc((long)NKV * DH * N_TOK * 2);
    float* o_f    = (float*)alloc((long)N_TOK * DM * 4);   // mid_bf alias
    float* coGu   = (float*)alloc((long)N_TOK * 3072 * 4); // opart+ml / co / gu_bf
    float* splitb = (float*)alloc((long)4 * N_TOK * DM * 4); // shared split-K partials
    bf16*  ctrlbf = (bf16*)alloc((long)N_TOK * CH * 2);
    int*   expert_id = (int*)alloc(N_TOK * 4);
    int*   perm      = (int*)alloc(N_TOK * 4);
    int*   counts    = (int*)alloc(64 * 4);
    int*   fill      = (int*)alloc(64 * 4);
    int*   offs      = (int*)alloc(64 * 4);

    bf16*  attn_bf = catA;                                  // catA dead after QKV gemm
    bf16*  x_bf    = (bf16*)xbuf;                           // x after k_ode
    bf16*  xg_bf   = (bf16*)xbuf + (long)N_TOK * DM;
    float* cpart   = (float*)((bf16*)xbuf + (long)2 * N_TOK * DM);  // 8*2048*64 fp32
    float* opart   = coGu;                                  // 2*2048*1024 fp32 (16 MB)
    float2* ml     = (float2*)(coGu + (long)2 * N_TOK * DM);
    float* co_f    = coGu;                                  // opart dead after merge
    bf16*  gu_bf   = (bf16*)coGu;                           // co dead after k_ode
    bf16*  mid_bf  = (bf16*)o_f;                            // o_f dead after k_ode

    dim3 blk(256);
    k_zero8<<<1, 64, 0, stream>>>(counts, fill);

    // ---- weight transposes (fp32 KxN -> bf16 NxK) ----
    k_transpose<<<dim3(16,16,1), blk, 0, stream>>>(wq, 0, 1024, WqkvT, 0, 2048);
    k_transpose<<<dim3(4,16,1),  blk, 0, stream>>>(wk, 0, 256,  WqkvT + (long)1024*2048, 0, 2048);
    k_transpose<<<dim3(4,16,1),  blk, 0, stream>>>(wv, 0, 256,  WqkvT + (long)1280*2048, 0, 2048);
    k_transpose<<<dim3(16,16,1), blk, 0, stream>>>(w_mu_q, 0, 1024, WqkvT + 1024, 0, 2048);
    k_transpose<<<dim3(4,16,1),  blk, 0, stream>>>(w_mu_k, 0, 256,  WqkvT + (long)1024*2048 + 1024, 0, 2048);
    k_transpose<<<dim3(4,16,1),  blk, 0, stream>>>(w_mu_v, 0, 256,  WqkvT + (long)1280*2048 + 1024, 0, 2048);
    k_transpose<<<dim3(16,16,1), blk, 0, stream>>>(wo, 0, 1024, woT, 0, 1024);
    k_transpose<<<dim3(16,16,1), blk, 0, stream>>>(dyn_proj, 0, 1024, dynT, 0, 1024);
    k_transpose<<<dim3(1,32,1),  blk, 0, stream>>>(ctrl_in_w, 0, 64, ctrlinT, 0, 2048);
    k_transpose<<<dim3(48,1,1),  blk, 0, stream>>>(ctrl_out_w, 0, 3072, ctrloutT, 0, 64);
    k_transpose<<<dim3(32,16,NE), blk, 0, stream>>>(w_gate, (long)1024*2048, 2048,
        gupT, (long)4096*1024, 1024);
    k_transpose<<<dim3(32,16,NE), blk, 0, stream>>>(w_up, (long)1024*2048, 2048,
        gupT + (long)2048*1024, (long)4096*1024, 1024);
    k_transpose<<<dim3(16,32,NE), blk, 0, stream>>>(w_down, (long)2048*1024, 1024,
        downT, (long)1024*2048, 2048);

    // ---- activation prep (rmsnorm + 2 casts fused) ----
    k_prep<<<N_TOK, blk, 0, stream>>>(hidden, ln1_w, mu_prev, velocity, catA, ctrlA);

    // ---- QKV: [h|mu] @ [Wqkv; Wmu]  split-K2 -> partials in splitb ----
    k_gemm<<<dim3(12,16,2), blk, 0, stream>>>(catA, 2048, WqkvT, 2048, 0,
        splitb, 1536, nullptr, nullptr, 0, 2048, 0, 2, (long)N_TOK * 1536,
        nullptr, nullptr, nullptr);

    k_qkv_post<<<N_TOK, blk, 0, stream>>>(splitb, positions, qnorm_w, knorm_w, q_bf, k_bf, v_bf);
    k_vt<<<dim3(32,1,NKV), blk, 0, stream>>>(v_bf, vt_bf);
    k_attn<<<dim3(32,16,2), blk, 0, stream>>>(q_bf, k_bf, vt_bf, opart, ml);
    k_attn_merge<<<N_TOK, blk, 0, stream>>>(opart, ml, attn_bf);

    // ---- o = attn @ wo  split-K2; reduce -> o_f fp32 + ctrlA bf16 ----
    k_gemm<<<dim3(8,16,2), blk, 0, stream>>>(attn_bf, 1024, woT, 1024, 0,
        splitb, 1024, nullptr, nullptr, 0, 1024, 0, 2, (long)N_TOK * DM,
        nullptr, nullptr, nullptr);
    k_red_wo<<<N_TOK, blk, 0, stream>>>(splitb, o_f, ctrlA);

    // ---- mu = dyn_mu + o @ dyn_proj  split-K2 (summed inside k_ode) ----
    k_gemm<<<dim3(8,16,2), blk, 0, stream>>>(ctrlA, 2048, dynT, 1024, 0,
        splitb, 1024, nullptr, nullptr, 0, 1024, 0, 2, (long)N_TOK * DM,
        nullptr, nullptr, nullptr);

    // ---- ctrl chain ----
    k_ctrl_gemm<<<dim3(16,8,1), blk, 0, stream>>>(ctrlA, ctrlinT, cpart);
    k_silu_ctrl<<<(N_TOK * CH) / 256, blk, 0, stream>>>(cpart, ctrl_in_b, ctrlbf);
    k_gemm<<<dim3(24,16,1), blk, 0, stream>>>(ctrlbf, 64, ctrloutT, 64, 0,
        co_f, 3072, ctrl_out_b, nullptr, 0, 64, GEMM_WRITE | GEMM_BIAS, 1, 0,
        nullptr, nullptr, nullptr);

    k_ode<<<N_TOK, blk, 0, stream>>>(co_f, o_f, velocity, splitb, dyn_mu, hidden,
        mu_router, token_ids, ln2_w, out0, out1, out2, x_bf, expert_id, counts);

    k_offsets<<<1, 64, 0, stream>>>(counts, offs);
    k_scatter<<<NE, blk, 0, stream>>>(expert_id, offs, fill, perm);
    k_gather<<<N_TOK, blk, 0, stream>>>(perm, x_bf, xg_bf);

    // ---- MoE: [gate|up] combined (N=4096), silu*mul, down split-K4 ----
    k_gemm<<<dim3(32,16,NE), blk, 0, stream>>>(xg_bf, 1024, gupT, 1024, (long)4096*1024,
        nullptr, 0, nullptr, gu_bf, 4096, 1024, GEMM_WRITEB, 1, 0,
        offs, nullptr, nullptr);
    k_silumul<<<(N_TOK * FF) / 256, blk, 0, stream>>>(gu_bf, mid_bf);
    k_gemm<<<dim3(8,16,NE*4), blk, 0, stream>>>(mid_bf, 2048, downT, 2048, (long)1024*2048,
        splitb, 1024, nullptr, nullptr, 0, 2048, 0, 4, (long)N_TOK * DM,
        offs, nullptr, nullptr);
    k_red_down<<<N_TOK, blk, 0, stream>>>(splitb, perm, out0);
}